// Round 1
// baseline (4139.929 us; speedup 1.0000x reference)
//
#include <hip/hip_runtime.h>

#define HW 200704          // 448*448
#define WIMG 448
#define NHEADS 6
#define DHEAD 30
#define NWIN 4096          // 64*64 windows of 7x7

static __device__ __forceinline__ unsigned short f2bf(float f) {
    union { float f; unsigned int u; } v; v.f = f;
    unsigned int u = v.u;
    unsigned int r = u + 0x7FFFu + ((u >> 16) & 1u);   // round-to-nearest-even
    return (unsigned short)(r >> 16);
}
static __device__ __forceinline__ float bf2f(unsigned short s) {
    union { unsigned int u; float f; } v; v.u = ((unsigned int)s) << 16;
    return v.f;
}

// ---------------------------------------------------------------------------
// conv1x1: out[b][oc][p] = sum_ic w[oc][ic] * x[b][ic][p],  IC = 180 fixed.
// Tile: 256 pixels x 60 out-channels per block. 256 threads.
//   lane = tid&63 handles 4 consecutive pixels; ty = tid>>6 handles 15 ocs.
// x tile staged in LDS in K-chunks of 45; weights via wave-uniform s_loads.
// ---------------------------------------------------------------------------
template <bool BF16OUT>
__global__ __launch_bounds__(256) void conv1x1_kernel(
    const float* __restrict__ x, const float* __restrict__ w,
    void* __restrict__ outv, int OC)
{
    const int b    = blockIdx.z;
    const int ocb  = blockIdx.y * 60;
    const int pix0 = blockIdx.x * 256;
    const int tid  = threadIdx.x;
    const int lane = tid & 63;
    const int ty   = __builtin_amdgcn_readfirstlane(tid >> 6);
    const int px   = lane * 4;

    __shared__ float xs[45 * 256];

    float acc[15][4];
#pragma unroll
    for (int r = 0; r < 15; ++r) {
        acc[r][0] = 0.f; acc[r][1] = 0.f; acc[r][2] = 0.f; acc[r][3] = 0.f;
    }

    for (int kc = 0; kc < 180; kc += 45) {
        for (int idx = tid; idx < 45 * 64; idx += 256) {
            int row = idx >> 6;
            int c4  = (idx & 63) * 4;
            *(float4*)(xs + row * 256 + c4) =
                *(const float4*)(x + ((size_t)b * 180 + kc + row) * HW + pix0 + c4);
        }
        __syncthreads();

        const float* wbase = w + (size_t)(ocb + ty * 15) * 180 + kc;
        for (int k = 0; k < 45; ++k) {
            float4 xv = *(const float4*)(xs + k * 256 + px);
#pragma unroll
            for (int r = 0; r < 15; ++r) {
                float wv = wbase[r * 180 + k];
                acc[r][0] += wv * xv.x;
                acc[r][1] += wv * xv.y;
                acc[r][2] += wv * xv.z;
                acc[r][3] += wv * xv.w;
            }
        }
        __syncthreads();
    }

    if (BF16OUT) {
        unsigned short* out = (unsigned short*)outv;
#pragma unroll
        for (int r = 0; r < 15; ++r) {
            int oc = ocb + ty * 15 + r;
            ushort4 u;
            u.x = f2bf(acc[r][0]); u.y = f2bf(acc[r][1]);
            u.z = f2bf(acc[r][2]); u.w = f2bf(acc[r][3]);
            *(ushort4*)(out + ((size_t)b * OC + oc) * HW + pix0 + px) = u;
        }
    } else {
        float* out = (float*)outv;
#pragma unroll
        for (int r = 0; r < 15; ++r) {
            int oc = ocb + ty * 15 + r;
            float4 v; v.x = acc[r][0]; v.y = acc[r][1]; v.z = acc[r][2]; v.w = acc[r][3];
            *(float4*)(out + ((size_t)b * OC + oc) * HW + pix0 + px) = v;
        }
    }
}

// ---------------------------------------------------------------------------
// Fused: depthwise 3x3 (SAME) + window rearrange + l2norm(q,k) + QK^T
//        + softmax + PV, per (b, window, head). Block = 256 threads.
// Reads bf16 qkv (pre-dwconv) with a 9x9 halo region per window.
// ---------------------------------------------------------------------------
__global__ __launch_bounds__(256) void attn_kernel(
    const unsigned short* __restrict__ A,   // bf16 [B][540][448][448]
    const float* __restrict__ wdw,          // [540][9]
    const float* __restrict__ temperature,  // [6]
    float* __restrict__ Cbuf)               // fp32 [B][180][448][448]
{
    const int win  = blockIdx.x;            // 0..4095
    const int head = blockIdx.y;            // 0..5
    const int b    = blockIdx.z;
    const int wy = win >> 6, wx = win & 63;
    const int h0 = wy * 7, w0 = wx * 7;
    const int tid = threadIdx.x;

    __shared__ float As[90 * 81];     // 9x9 halo region, 90 channels (q,k,v x 30)
    __shared__ float wdws[90 * 9];
    __shared__ float qs[30 * 52];     // rows padded 49->52 (zero fill)
    __shared__ float ks[30 * 52];
    __shared__ float vs[30 * 52];
    __shared__ float attns[30 * 32];
    __shared__ float invq[30], invk[30];

    const float temp = temperature[head];

    // stage depthwise weights for our 90 channels
    for (int idx = tid; idx < 90 * 9; idx += 256) {
        int c = idx / 9, t = idx - c * 9;
        int cg = (c / 30) * 180 + head * 30 + (c - (c / 30) * 30);
        wdws[idx] = wdw[cg * 9 + t];
    }
    // stage 9x9 halo region of A (zero-padded at image borders)
    for (int idx = tid; idx < 90 * 81; idx += 256) {
        int c = idx / 81, pos = idx - c * 81;
        int iy = pos / 9 - 1;
        int ix = pos - (pos / 9) * 9 - 1;
        int y = h0 + iy, x = w0 + ix;
        float v = 0.f;
        if ((unsigned)y < 448u && (unsigned)x < 448u) {
            int cg = (c / 30) * 180 + head * 30 + (c - (c / 30) * 30);
            v = bf2f(A[((size_t)b * 540 + cg) * HW + y * WIMG + x]);
        }
        As[idx] = v;
    }
    __syncthreads();

    // depthwise 3x3 -> q/k/v tiles [30][52]
    for (int idx = tid; idx < 90 * 52; idx += 256) {
        int c = idx / 52, pos = idx - c * 52;
        float acc = 0.f;
        if (pos < 49) {
            int ph = pos / 7, pw = pos - (pos / 7) * 7;
            const float* a  = &As[c * 81 + ph * 9 + pw];
            const float* wv = &wdws[c * 9];
#pragma unroll
            for (int ky = 0; ky < 3; ++ky)
#pragma unroll
                for (int kx = 0; kx < 3; ++kx)
                    acc += a[ky * 9 + kx] * wv[ky * 3 + kx];
        }
        int part = c / 30, dc = c - part * 30;
        float* dst = (part == 0) ? qs : (part == 1) ? ks : vs;
        dst[dc * 52 + pos] = acc;
    }
    __syncthreads();

    // l2 norms of q,k rows
    if (tid < 60) {
        const float* src = (tid < 30) ? qs : ks;
        int r = (tid < 30) ? tid : tid - 30;
        float s = 0.f;
        for (int p = 0; p < 49; ++p) { float v = src[r * 52 + p]; s += v * v; }
        float inv = 1.f / fmaxf(sqrtf(s), 1e-12f);
        if (tid < 30) invq[r] = inv; else invk[r] = inv;
    }
    __syncthreads();

    // attn[i][j] = (q_i . k_j) * invq[i]*invk[j]*temp   (2x2 register tile)
    if (tid < 225) {
        int i0 = (tid / 15) * 2, j0 = (tid - (tid / 15) * 15) * 2;
        float d00 = 0.f, d01 = 0.f, d10 = 0.f, d11 = 0.f;
#pragma unroll
        for (int p4 = 0; p4 < 13; ++p4) {
            float4 qa = *(const float4*)&qs[i0 * 52 + p4 * 4];
            float4 qb = *(const float4*)&qs[(i0 + 1) * 52 + p4 * 4];
            float4 ka = *(const float4*)&ks[j0 * 52 + p4 * 4];
            float4 kb = *(const float4*)&ks[(j0 + 1) * 52 + p4 * 4];
            d00 += qa.x * ka.x + qa.y * ka.y + qa.z * ka.z + qa.w * ka.w;
            d01 += qa.x * kb.x + qa.y * kb.y + qa.z * kb.z + qa.w * kb.w;
            d10 += qb.x * ka.x + qb.y * ka.y + qb.z * ka.z + qb.w * ka.w;
            d11 += qb.x * kb.x + qb.y * kb.y + qb.z * kb.z + qb.w * kb.w;
        }
        attns[i0 * 32 + j0]           = d00 * invq[i0] * invk[j0] * temp;
        attns[i0 * 32 + j0 + 1]       = d01 * invq[i0] * invk[j0 + 1] * temp;
        attns[(i0 + 1) * 32 + j0]     = d10 * invq[i0 + 1] * invk[j0] * temp;
        attns[(i0 + 1) * 32 + j0 + 1] = d11 * invq[i0 + 1] * invk[j0 + 1] * temp;
    }
    __syncthreads();

    // row softmax over j (30 entries)
    if (tid < 30) {
        float m = -1e30f;
        for (int j = 0; j < 30; ++j) m = fmaxf(m, attns[tid * 32 + j]);
        float s = 0.f;
        for (int j = 0; j < 30; ++j) {
            float e = expf(attns[tid * 32 + j] - m);
            attns[tid * 32 + j] = e;
            s += e;
        }
        float inv = 1.f / s;
        for (int j = 0; j < 30; ++j) attns[tid * 32 + j] *= inv;
    }
    __syncthreads();

    // out[i][p] = sum_j attn[i][j] * v[j][p]; write to Cbuf in NCHW
    if (tid < 195) {
        int i0 = (tid / 13) * 2;
        int q4 = tid - (tid / 13) * 13;
        float a0[4] = {0.f, 0.f, 0.f, 0.f};
        float a1[4] = {0.f, 0.f, 0.f, 0.f};
#pragma unroll
        for (int j = 0; j < 30; ++j) {
            float w0a = attns[i0 * 32 + j];
            float w1a = attns[(i0 + 1) * 32 + j];
            float4 vv = *(const float4*)&vs[j * 52 + q4 * 4];
            a0[0] += w0a * vv.x; a0[1] += w0a * vv.y; a0[2] += w0a * vv.z; a0[3] += w0a * vv.w;
            a1[0] += w1a * vv.x; a1[1] += w1a * vv.y; a1[2] += w1a * vv.z; a1[3] += w1a * vv.w;
        }
        size_t base = ((size_t)b * 180 + head * 30) * (size_t)HW;
#pragma unroll
        for (int e = 0; e < 4; ++e) {
            int p = q4 * 4 + e;
            if (p < 49) {
                int ph = p / 7, pw = p - ph * 7;
                size_t off = (size_t)(h0 + ph) * WIMG + (w0 + pw);
                Cbuf[base + (size_t)i0 * HW + off]       = a0[e];
                Cbuf[base + (size_t)(i0 + 1) * HW + off] = a1[e];
            }
        }
    }
}

extern "C" void kernel_launch(void* const* d_in, const int* in_sizes, int n_in,
                              void* d_out, int out_size, void* d_ws, size_t ws_size,
                              hipStream_t stream) {
    const float* x           = (const float*)d_in[0];
    const float* temperature = (const float*)d_in[1];
    const float* w_qkv       = (const float*)d_in[2];
    const float* w_dw        = (const float*)d_in[3];
    const float* w_proj      = (const float*)d_in[4];
    float* out = (float*)d_out;

    // workspace: bf16 qkv [2][540][448][448] = 433,520,640 B
    //            fp32 attn-out [2][180][448][448] = 289,013,760 B
    const size_t A_BYTES = 433520640ull;
    const size_t NEEDED  = A_BYTES + 289013760ull;
    if (ws_size < NEEDED) return;  // fail loudly via validation

    unsigned short* A = (unsigned short*)d_ws;
    float* Cbuf = (float*)((char*)d_ws + A_BYTES);

    // 1) qkv = conv1x1(x, w_qkv)  -> bf16 A
    dim3 g1(HW / 256, 540 / 60, 2);
    conv1x1_kernel<true><<<g1, 256, 0, stream>>>(x, w_qkv, (void*)A, 540);

    // 2) fused dwconv + window channel attention -> fp32 Cbuf
    dim3 g2(NWIN, NHEADS, 2);
    attn_kernel<<<g2, 256, 0, stream>>>(A, w_dw, temperature, Cbuf);

    // 3) out = conv1x1(Cbuf, w_proj)
    dim3 g3(HW / 256, 180 / 60, 2);
    conv1x1_kernel<false><<<g3, 256, 0, stream>>>(Cbuf, w_proj, (void*)out, 180);
}

// Round 2
// 2535.305 us; speedup vs baseline: 1.6329x; 1.6329x over previous
//
#include <hip/hip_runtime.h>

#define HW 200704          // 448*448
#define WIMG 448

typedef __attribute__((ext_vector_type(4))) unsigned int u32x4;
typedef __attribute__((ext_vector_type(4))) float f32x4;
typedef __attribute__((ext_vector_type(8))) short s16x8;

static __device__ __forceinline__ unsigned short f2bf(float f) {
    union { float f; unsigned int u; } v; v.f = f;
    unsigned int u = v.u;
    unsigned int r = u + 0x7FFFu + ((u >> 16) & 1u);   // RNE
    return (unsigned short)(r >> 16);
}
static __device__ __forceinline__ float bf2f(unsigned short s) {
    union { unsigned int u; float f; } v; v.u = ((unsigned int)s) << 16;
    return v.f;
}

// ---------------------------------------------------------------------------
// K1: qkv = conv1x1(x, w_qkv), fp32 in -> bf16 out. 256 px x 60 oc per block.
// ---------------------------------------------------------------------------
__global__ __launch_bounds__(256) void qkv_conv_kernel(
    const float* __restrict__ x, const float* __restrict__ w,
    unsigned short* __restrict__ out)
{
    const int b    = blockIdx.z;
    const int ocb  = blockIdx.y * 60;
    const int pix0 = blockIdx.x * 256;
    const int tid  = threadIdx.x;
    const int lane = tid & 63;
    const int ty   = __builtin_amdgcn_readfirstlane(tid >> 6);
    const int px   = lane * 4;

    __shared__ float xs[45 * 256];

    float acc[15][4];
#pragma unroll
    for (int r = 0; r < 15; ++r)
        acc[r][0] = acc[r][1] = acc[r][2] = acc[r][3] = 0.f;

    for (int kc = 0; kc < 180; kc += 45) {
        for (int idx = tid; idx < 45 * 64; idx += 256) {
            int row = idx >> 6;
            int c4  = (idx & 63) * 4;
            *(float4*)(xs + row * 256 + c4) =
                *(const float4*)(x + ((size_t)b * 180 + kc + row) * HW + pix0 + c4);
        }
        __syncthreads();
        const float* wbase = w + (size_t)(ocb + ty * 15) * 180 + kc;
        for (int k = 0; k < 45; ++k) {
            float4 xv = *(const float4*)(xs + k * 256 + px);
#pragma unroll
            for (int r = 0; r < 15; ++r) {
                float wv = wbase[r * 180 + k];
                acc[r][0] += wv * xv.x; acc[r][1] += wv * xv.y;
                acc[r][2] += wv * xv.z; acc[r][3] += wv * xv.w;
            }
        }
        __syncthreads();
    }
#pragma unroll
    for (int r = 0; r < 15; ++r) {
        int oc = ocb + ty * 15 + r;
        ushort4 u;
        u.x = f2bf(acc[r][0]); u.y = f2bf(acc[r][1]);
        u.z = f2bf(acc[r][2]); u.w = f2bf(acc[r][3]);
        *(ushort4*)(out + ((size_t)b * 540 + oc) * HW + pix0 + px) = u;
    }
}

// ---------------------------------------------------------------------------
// K2a: depthwise 3x3 (SAME) + window rearrange.
// In : bf16 A [b][540][448][448]   Out: bf16 Bw [b][win][head][3][30][49]
// Block: (wrow, c, b), 448 threads = one image row strip; register-rolling rows.
// ---------------------------------------------------------------------------
__global__ __launch_bounds__(448) void dw_kernel(
    const unsigned short* __restrict__ A, const float* __restrict__ wdw,
    unsigned short* __restrict__ Bw)
{
    const int wrow = blockIdx.x;   // 0..63
    const int c    = blockIdx.y;   // 0..539
    const int b    = blockIdx.z;
    const int x    = threadIdx.x;  // 0..447

    const int part = c / 180;
    const int rem  = c - part * 180;
    const int head = rem / 30;
    const int dc   = rem - head * 30;

    float w[9];
#pragma unroll
    for (int i = 0; i < 9; ++i) w[i] = wdw[c * 9 + i];

    const unsigned short* Ac = A + ((size_t)b * 540 + c) * HW;
    const int xdiv = x / 7;
    const int win  = wrow * 64 + xdiv;
    const int pw   = x - xdiv * 7;
    const size_t obase =
        ((((size_t)(b * 4096 + win) * 6 + head) * 3 + part) * 30 + dc) * 49 + pw;

    const int xm = x - 1, xp = x + 1;
    float a0L, a0C, a0R, a1L, a1C, a1R, a2L, a2C, a2R;
    const int y0 = wrow * 7;

    auto ldrow = [&](int yy, float& L, float& C, float& R) {
        if ((unsigned)yy < 448u) {
            const unsigned short* row = Ac + (size_t)yy * WIMG;
            L = (xm >= 0)  ? bf2f(row[xm]) : 0.f;
            C = bf2f(row[x]);
            R = (xp < 448) ? bf2f(row[xp]) : 0.f;
        } else { L = C = R = 0.f; }
    };
    ldrow(y0 - 1, a0L, a0C, a0R);
    ldrow(y0,     a1L, a1C, a1R);
#pragma unroll
    for (int ph = 0; ph < 7; ++ph) {
        ldrow(y0 + ph + 1, a2L, a2C, a2R);
        float acc = w[0]*a0L + w[1]*a0C + w[2]*a0R
                  + w[3]*a1L + w[4]*a1C + w[5]*a1R
                  + w[6]*a2L + w[7]*a2C + w[8]*a2R;
        Bw[obase + ph * 7] = f2bf(acc);
        a0L=a1L; a0C=a1C; a0R=a1R; a1L=a2L; a1C=a2C; a1R=a2R;
    }
}

// ---------------------------------------------------------------------------
// K2b: per-(b,win,head) channel attention, one wave per unit, 4 units/block.
// MFMA 16x16x32 bf16 for QK^T, norms (diag of QQ^T/KK^T), and PV.
// In : Bw [unit][3][30][49] bf16   Out: Cw [unit][30][49] bf16
// ---------------------------------------------------------------------------
__global__ __launch_bounds__(256) void attn2_kernel(
    const unsigned short* __restrict__ Bw,
    const float* __restrict__ temperature,
    unsigned short* __restrict__ Cw)
{
    __shared__ __align__(16) unsigned short lds[4][6144]; // Q[2048] K[2048] Vt[2048] per wave
    __shared__ float invs[4][64];                         // invq[32], invk[32]

    const int w    = threadIdx.x >> 6;
    const int l    = threadIdx.x & 63;
    const int unit = blockIdx.x * 4 + w;          // (b*4096+win)*6+head
    const int head = unit % 6;
    const float temp = temperature[head];
    unsigned short* U = lds[w];
    float* inv = invs[w];
    const int r15 = l & 15;
    const int g4  = l >> 4;

    // zero LDS (padding rows/cols must be 0)
    {
        const u32x4 vz = {0u, 0u, 0u, 0u};
        u32x4* Z = (u32x4*)U;
#pragma unroll
        for (int i = 0; i < 12; ++i) Z[i * 64 + l] = vz;
    }
    __syncthreads();

    // stage 4410 bf16 contiguous -> swizzled LDS
    {
        const unsigned short* src = Bw + (size_t)unit * 4410;
        for (int t = 0; t < 35; ++t) {
            int d = t * 64 + l;
            if (d < 2205) {
                unsigned int v2 = *(const unsigned int*)(src + 2 * d);
                int e = 2 * d;
                int part = e / 1470;
                int rem  = e - part * 1470;
                int dc   = rem / 49;
                int p    = rem - dc * 49;
#pragma unroll
                for (int half = 0; half < 2; ++half) {
                    unsigned short val = (half == 0) ? (unsigned short)(v2 & 0xffffu)
                                                     : (unsigned short)(v2 >> 16);
                    if (part < 2) {   // Q/K: row=dc (stride 64), col=p, XOR(row&7) on 8-groups
                        int col = (((p >> 3) ^ (dc & 7)) << 3) | (p & 7);
                        U[part * 2048 + dc * 64 + col] = val;
                    } else {          // Vt: row=p (stride 32), col=dc, XOR(row&3)
                        int col = (((dc >> 3) ^ (p & 3)) << 3) | (dc & 7);
                        U[4096 + p * 32 + col] = val;
                    }
                    ++p;
                    if (p == 49) { p = 0; ++dc; if (dc == 30) { dc = 0; ++part; } }
                }
            }
        }
    }
    __syncthreads();

    // fragment loads: A[m][k]: lane -> row=(l&15), k=(l>>4)*8+e  (b128 each)
    s16x8 aQ[2][2], bK[2][2];
#pragma unroll
    for (int mi = 0; mi < 2; ++mi)
#pragma unroll
        for (int kk = 0; kk < 2; ++kk) {
            int r  = mi * 16 + r15;
            int gk = kk * 4 + g4;
            int so = ((gk ^ (r & 7)) << 3);
            aQ[mi][kk] = __builtin_bit_cast(s16x8, *(const u32x4*)(U + r * 64 + so));
            bK[mi][kk] = __builtin_bit_cast(s16x8, *(const u32x4*)(U + 2048 + r * 64 + so));
        }

    f32x4 s[2][2], dq[2], dk[2];
#pragma unroll
    for (int mi = 0; mi < 2; ++mi) {
        dq[mi] = (f32x4){0.f, 0.f, 0.f, 0.f};
        dk[mi] = (f32x4){0.f, 0.f, 0.f, 0.f};
#pragma unroll
        for (int nj = 0; nj < 2; ++nj) s[mi][nj] = (f32x4){0.f, 0.f, 0.f, 0.f};
    }

#pragma unroll
    for (int kk = 0; kk < 2; ++kk) {
#pragma unroll
        for (int mi = 0; mi < 2; ++mi) {
#pragma unroll
            for (int nj = 0; nj < 2; ++nj)
                s[mi][nj] = __builtin_amdgcn_mfma_f32_16x16x32_bf16(
                    aQ[mi][kk], bK[nj][kk], s[mi][nj], 0, 0, 0);
            // A-frag == B-frag addressing: diag(Q.Q^T)=|q_i|^2, diag(K.K^T)=|k_j|^2
            dq[mi] = __builtin_amdgcn_mfma_f32_16x16x32_bf16(
                aQ[mi][kk], aQ[mi][kk], dq[mi], 0, 0, 0);
            dk[mi] = __builtin_amdgcn_mfma_f32_16x16x32_bf16(
                bK[mi][kk], bK[mi][kk], dk[mi], 0, 0, 0);
        }
    }

    // diagonal -> inverse norms
#pragma unroll
    for (int mi = 0; mi < 2; ++mi)
#pragma unroll
        for (int reg = 0; reg < 4; ++reg) {
            int row = g4 * 4 + reg;                 // D: row=(l>>4)*4+reg, col=l&15
            if (row == r15) {
                inv[mi * 16 + row]      = 1.f / fmaxf(sqrtf(dq[mi][reg]), 1e-12f);
                inv[32 + mi * 16 + row] = 1.f / fmaxf(sqrtf(dk[mi][reg]), 1e-12f);
            }
        }
    __syncthreads();

    // scale + mask + softmax (rows live in 16-lane groups)
    float pr[2][2][4];
    float cinvk0 = inv[32 + r15];
    float cinvk1 = inv[32 + 16 + r15];
#pragma unroll
    for (int mi = 0; mi < 2; ++mi)
#pragma unroll
        for (int reg = 0; reg < 4; ++reg) {
            float qi = inv[mi * 16 + g4 * 4 + reg];
            float v0 = s[mi][0][reg] * qi * cinvk0 * temp;
            float v1 = s[mi][1][reg] * qi * cinvk1 * temp;
            if (16 + r15 >= 30) v1 = -1e30f;        // mask cols 30,31
            float m = fmaxf(v0, v1);
#pragma unroll
            for (int off = 1; off < 16; off <<= 1) m = fmaxf(m, __shfl_xor(m, off));
            float e0 = __expf(v0 - m);
            float e1 = __expf(v1 - m);
            float sum = e0 + e1;
#pragma unroll
            for (int off = 1; off < 16; off <<= 1) sum += __shfl_xor(sum, off);
            float rs = 1.f / sum;
            pr[mi][0][reg] = e0 * rs;
            pr[mi][1][reg] = e1 * rs;
        }

    // write P (bf16) into Q region [32][32], XOR(row&3) swizzle
#pragma unroll
    for (int mi = 0; mi < 2; ++mi)
#pragma unroll
        for (int nj = 0; nj < 2; ++nj)
#pragma unroll
            for (int reg = 0; reg < 4; ++reg) {
                int row = mi * 16 + g4 * 4 + reg;
                int col = nj * 16 + r15;
                int scol = (((col >> 3) ^ (row & 3)) << 3) | (col & 7);
                U[row * 32 + scol] = f2bf(pr[mi][nj][reg]);
            }
    __syncthreads();

    // PV: out[32][64] = P[32][32] . V[32][64]  (B from Vt, single K-step)
    s16x8 aP[2], bV[4];
#pragma unroll
    for (int mi = 0; mi < 2; ++mi) {
        int i = mi * 16 + r15;
        aP[mi] = __builtin_bit_cast(s16x8,
                 *(const u32x4*)(U + i * 32 + ((g4 ^ (i & 3)) << 3)));
    }
#pragma unroll
    for (int nt = 0; nt < 4; ++nt) {
        int p = nt * 16 + r15;
        bV[nt] = __builtin_bit_cast(s16x8,
                 *(const u32x4*)(U + 4096 + p * 32 + ((g4 ^ (p & 3)) << 3)));
    }
    f32x4 o[2][4];
#pragma unroll
    for (int mi = 0; mi < 2; ++mi)
#pragma unroll
        for (int nt = 0; nt < 4; ++nt) {
            o[mi][nt] = (f32x4){0.f, 0.f, 0.f, 0.f};
            o[mi][nt] = __builtin_amdgcn_mfma_f32_16x16x32_bf16(
                aP[mi], bV[nt], o[mi][nt], 0, 0, 0);
        }

    // store valid 30x49 as bf16
    unsigned short* dst = Cw + (size_t)unit * 1470;
#pragma unroll
    for (int mi = 0; mi < 2; ++mi)
#pragma unroll
        for (int reg = 0; reg < 4; ++reg) {
            int i = mi * 16 + g4 * 4 + reg;
            if (i < 30) {
#pragma unroll
                for (int nt = 0; nt < 4; ++nt) {
                    int p = nt * 16 + r15;
                    if (p < 49) dst[i * 49 + p] = f2bf(o[mi][nt][reg]);
                }
            }
        }
}

// ---------------------------------------------------------------------------
// K3: out = conv1x1(attn_out, w_proj); input in window layout bf16
// Cw [b][win][180][49]; output NCHW fp32.
// ---------------------------------------------------------------------------
__global__ __launch_bounds__(256) void proj_kernel(
    const unsigned short* __restrict__ Cw, const float* __restrict__ w,
    float* __restrict__ out)
{
    const int b   = blockIdx.z;
    const int ocb = blockIdx.y * 60;
    const int P0  = blockIdx.x * 256;
    const int tid  = threadIdx.x;
    const int lane = tid & 63;
    const int ty   = __builtin_amdgcn_readfirstlane(tid >> 6);
    const int px   = lane * 4;

    __shared__ float xs[45 * 256];

    // staging source mapping (one pixel per thread)
    const int Pst = P0 + tid;
    const int wns = Pst / 49, pps = Pst - wns * 49;
    const unsigned short* cb = Cw + ((size_t)(b * 4096 + wns) * 180) * 49 + pps;

    // output mapping for this thread's 4 pixels
    size_t poff[4];
#pragma unroll
    for (int e = 0; e < 4; ++e) {
        int P = P0 + px + e;
        int wn = P / 49, p = P - wn * 49;
        int ph = p / 7;
        poff[e] = (size_t)((wn >> 6) * 7 + ph) * WIMG + (wn & 63) * 7 + (p - ph * 7);
    }

    float acc[15][4];
#pragma unroll
    for (int r = 0; r < 15; ++r)
        acc[r][0] = acc[r][1] = acc[r][2] = acc[r][3] = 0.f;

    for (int kc = 0; kc < 180; kc += 45) {
        for (int it = 0; it < 45; ++it)
            xs[it * 256 + tid] = bf2f(cb[(size_t)(kc + it) * 49]);
        __syncthreads();
        const float* wbase = w + (size_t)(ocb + ty * 15) * 180 + kc;
        for (int k = 0; k < 45; ++k) {
            float4 xv = *(const float4*)(xs + k * 256 + px);
#pragma unroll
            for (int r = 0; r < 15; ++r) {
                float wv = wbase[r * 180 + k];
                acc[r][0] += wv * xv.x; acc[r][1] += wv * xv.y;
                acc[r][2] += wv * xv.z; acc[r][3] += wv * xv.w;
            }
        }
        __syncthreads();
    }

    float* ob = out + (size_t)b * 180 * (size_t)HW;
#pragma unroll
    for (int r = 0; r < 15; ++r) {
        int oc = ocb + ty * 15 + r;
#pragma unroll
        for (int e = 0; e < 4; ++e)
            ob[(size_t)oc * HW + poff[e]] = acc[r][e];
    }
}

extern "C" void kernel_launch(void* const* d_in, const int* in_sizes, int n_in,
                              void* d_out, int out_size, void* d_ws, size_t ws_size,
                              hipStream_t stream) {
    const float* x           = (const float*)d_in[0];
    const float* temperature = (const float*)d_in[1];
    const float* w_qkv       = (const float*)d_in[2];
    const float* w_dw        = (const float*)d_in[3];
    const float* w_proj      = (const float*)d_in[4];
    float* out = (float*)d_out;

    const size_t A_BYTES = 433520640ull;   // bf16 [2][540][448][448]
    if (ws_size < 2 * A_BYTES) return;

    unsigned short* A  = (unsigned short*)d_ws;                       // qkv NCHW bf16
    unsigned short* Bw = (unsigned short*)((char*)d_ws + A_BYTES);    // window-major bf16
    unsigned short* Cw = A;                                           // overlay: A dead after dw_kernel

    qkv_conv_kernel<<<dim3(HW / 256, 9, 2), 256, 0, stream>>>(x, w_qkv, A);
    dw_kernel<<<dim3(64, 540, 2), 448, 0, stream>>>(A, w_dw, Bw);
    attn2_kernel<<<dim3(12288, 1, 1), 256, 0, stream>>>(Bw, temperature, Cw);
    proj_kernel<<<dim3(HW / 256, 3, 2), 256, 0, stream>>>(Cw, w_proj, out);
}

// Round 3
// 1892.067 us; speedup vs baseline: 2.1880x; 1.3400x over previous
//
#include <hip/hip_runtime.h>

#define HW 200704          // 448*448
#define WIMG 448

typedef __attribute__((ext_vector_type(4))) unsigned int u32x4;
typedef __attribute__((ext_vector_type(4))) float f32x4;
typedef __attribute__((ext_vector_type(8))) short s16x8;

static __device__ __forceinline__ unsigned short f2bf(float f) {
    union { float f; unsigned int u; } v; v.f = f;
    unsigned int u = v.u;
    unsigned int r = u + 0x7FFFu + ((u >> 16) & 1u);   // RNE
    return (unsigned short)(r >> 16);
}
static __device__ __forceinline__ float bf2f(unsigned short s) {
    union { unsigned int u; float f; } v; v.u = ((unsigned int)s) << 16;
    return v.f;
}

// ---------------------------------------------------------------------------
// K0: transpose+cast  x fp32 [b][180][HW]  ->  xT bf16 [b][HW][192] (K-pad 0)
// ---------------------------------------------------------------------------
__global__ __launch_bounds__(256) void transpose_cast_kernel(
    const float* __restrict__ x, unsigned short* __restrict__ xT)
{
    const int bi = blockIdx.y;
    const int p0 = blockIdx.x * 64;
    const int tid = threadIdx.x;
    const int pl = tid & 63;

    __shared__ float T[180 * 65];

    for (int ic = tid >> 6; ic < 180; ic += 4)
        T[ic * 65 + pl] = x[((size_t)bi * 180 + ic) * HW + p0 + pl];
    __syncthreads();

    const int cg = tid >> 6;
    unsigned short* drow = xT + ((size_t)bi * HW + p0 + pl) * 192;
#pragma unroll
    for (int i = 0; i < 6; ++i) {
        int k0 = (cg * 6 + i) * 8;
        unsigned short u[8];
#pragma unroll
        for (int e = 0; e < 8; ++e)
            u[e] = (k0 + e < 180) ? f2bf(T[(k0 + e) * 65 + pl]) : (unsigned short)0;
        *(u32x4*)(drow + k0) = *(const u32x4*)u;
    }
}

// ---------------------------------------------------------------------------
// K1: qkv GEMM via MFMA.  A-op = w_qkv (bf16 in LDS), B-op = xT rows.
// Tile: 64 oc x 256 px, 4 waves (each: all 4 M-frags x 64 own pixels).
// Out: bf16 NCHW [b][540][HW].
// ---------------------------------------------------------------------------
__global__ __launch_bounds__(256) void gemm_qkv_kernel(
    const unsigned short* __restrict__ xT, const float* __restrict__ wq,
    unsigned short* __restrict__ A)
{
    const int bi   = blockIdx.z;
    const int ocb  = blockIdx.y * 64;
    const int pix0 = blockIdx.x * 256;
    const int tid  = threadIdx.x;
    const int l    = tid & 63;
    const int w    = tid >> 6;
    const int r15  = l & 15;
    const int g4   = l >> 4;

    __shared__ __align__(16) unsigned short wlds[64 * 200];
    __shared__ __align__(16) unsigned short xs[256 * 40];

    // weights -> bf16 LDS [64][192 used of 200], zero-padded
    for (int idx = tid; idx < 64 * 24; idx += 256) {
        int row = idx / 24, ch = idx - (idx / 24) * 24;
        int oc = ocb + row;
        unsigned short u[8];
#pragma unroll
        for (int e = 0; e < 8; ++e) {
            int k = ch * 8 + e;
            u[e] = (oc < 540 && k < 180) ? f2bf(wq[oc * 180 + k]) : (unsigned short)0;
        }
        *(u32x4*)(wlds + row * 200 + ch * 8) = *(const u32x4*)u;
    }

    // staging row pointers (4 pixels per thread, one 8-k chunk each)
    const unsigned short* srow[4];
#pragma unroll
    for (int i = 0; i < 4; ++i)
        srow[i] = xT + ((size_t)bi * HW + pix0 + i * 64 + (tid >> 2)) * 192 + (tid & 3) * 8;
    const int sdst = (tid >> 2) * 40 + (tid & 3) * 8;   // per-i add i*64*40

    f32x4 acc[4][4];
#pragma unroll
    for (int mi = 0; mi < 4; ++mi)
#pragma unroll
        for (int nt = 0; nt < 4; ++nt) acc[mi][nt] = (f32x4){0.f, 0.f, 0.f, 0.f};

    for (int ks = 0; ks < 6; ++ks) {
        __syncthreads();
#pragma unroll
        for (int i = 0; i < 4; ++i)
            *(u32x4*)(xs + sdst + i * 64 * 40) = *(const u32x4*)(srow[i] + ks * 32);
        __syncthreads();

        s16x8 aW[4], bX[4];
#pragma unroll
        for (int mi = 0; mi < 4; ++mi)
            aW[mi] = __builtin_bit_cast(s16x8,
                     *(const u32x4*)(wlds + (mi * 16 + r15) * 200 + ks * 32 + g4 * 8));
#pragma unroll
        for (int nt = 0; nt < 4; ++nt)
            bX[nt] = __builtin_bit_cast(s16x8,
                     *(const u32x4*)(xs + (w * 64 + nt * 16 + r15) * 40 + g4 * 8));
#pragma unroll
        for (int mi = 0; mi < 4; ++mi)
#pragma unroll
            for (int nt = 0; nt < 4; ++nt)
                acc[mi][nt] = __builtin_amdgcn_mfma_f32_16x16x32_bf16(
                    aW[mi], bX[nt], acc[mi][nt], 0, 0, 0);
    }

    // store bf16 NCHW: row = oc (g4*4+reg), col = pixel (r15)
#pragma unroll
    for (int mi = 0; mi < 4; ++mi) {
#pragma unroll
        for (int reg = 0; reg < 4; ++reg) {
            int oc = ocb + mi * 16 + g4 * 4 + reg;
            if (oc < 540) {
                unsigned short* orow = A + ((size_t)bi * 540 + oc) * HW + pix0 + w * 64;
#pragma unroll
                for (int nt = 0; nt < 4; ++nt)
                    orow[nt * 16 + r15] = f2bf(acc[mi][nt][reg]);
            }
        }
    }
}

// ---------------------------------------------------------------------------
// K2: depthwise 3x3 (SAME) + window rearrange.
// In : bf16 A [b][540][448][448]   Out: bf16 Bw [b][win][head][3][30][49]
// ---------------------------------------------------------------------------
__global__ __launch_bounds__(448) void dw_kernel(
    const unsigned short* __restrict__ A, const float* __restrict__ wdw,
    unsigned short* __restrict__ Bw)
{
    const int wrow = blockIdx.x;   // 0..63
    const int c    = blockIdx.y;   // 0..539
    const int b    = blockIdx.z;
    const int x    = threadIdx.x;  // 0..447

    const int part = c / 180;
    const int rem  = c - part * 180;
    const int head = rem / 30;
    const int dc   = rem - head * 30;

    float w[9];
#pragma unroll
    for (int i = 0; i < 9; ++i) w[i] = wdw[c * 9 + i];

    const unsigned short* Ac = A + ((size_t)b * 540 + c) * HW;
    const int xdiv = x / 7;
    const int win  = wrow * 64 + xdiv;
    const int pw   = x - xdiv * 7;
    const size_t obase =
        ((((size_t)(b * 4096 + win) * 6 + head) * 3 + part) * 30 + dc) * 49 + pw;

    const int xm = x - 1, xp = x + 1;
    float a0L, a0C, a0R, a1L, a1C, a1R, a2L, a2C, a2R;
    const int y0 = wrow * 7;

    auto ldrow = [&](int yy, float& L, float& C, float& R) {
        if ((unsigned)yy < 448u) {
            const unsigned short* row = Ac + (size_t)yy * WIMG;
            L = (xm >= 0)  ? bf2f(row[xm]) : 0.f;
            C = bf2f(row[x]);
            R = (xp < 448) ? bf2f(row[xp]) : 0.f;
        } else { L = C = R = 0.f; }
    };
    ldrow(y0 - 1, a0L, a0C, a0R);
    ldrow(y0,     a1L, a1C, a1R);
#pragma unroll
    for (int ph = 0; ph < 7; ++ph) {
        ldrow(y0 + ph + 1, a2L, a2C, a2R);
        float acc = w[0]*a0L + w[1]*a0C + w[2]*a0R
                  + w[3]*a1L + w[4]*a1C + w[5]*a1R
                  + w[6]*a2L + w[7]*a2C + w[8]*a2R;
        Bw[obase + ph * 7] = f2bf(acc);
        a0L=a1L; a0C=a1C; a0R=a1R; a1L=a2L; a1C=a2C; a1R=a2R;
    }
}

// ---------------------------------------------------------------------------
// K3: per-(b,win,head) channel attention, one wave per unit, 4 units/block.
// In : Bw [unit][3][30][49] bf16   Out: Cwt [b*4096+win][49][192] bf16
//      (ch = head*30 + d, K-pad 180..191 zeroed by head==5 waves)
// ---------------------------------------------------------------------------
__global__ __launch_bounds__(256) void attn2_kernel(
    const unsigned short* __restrict__ Bw,
    const float* __restrict__ temperature,
    unsigned short* __restrict__ Cwt)
{
    __shared__ __align__(16) unsigned short lds[4][6144];
    __shared__ float invs[4][64];

    const int w    = threadIdx.x >> 6;
    const int l    = threadIdx.x & 63;
    const int unit = blockIdx.x * 4 + w;          // (b*4096+win)*6+head
    const int u6   = unit / 6;
    const int head = unit - u6 * 6;
    const float temp = temperature[head];
    unsigned short* U = lds[w];
    float* inv = invs[w];
    const int r15 = l & 15;
    const int g4  = l >> 4;

    // zero LDS (padding rows/cols must be 0)
    {
        const u32x4 vz = {0u, 0u, 0u, 0u};
        u32x4* Z = (u32x4*)U;
#pragma unroll
        for (int i = 0; i < 12; ++i) Z[i * 64 + l] = vz;
    }
    __syncthreads();

    // stage 4410 bf16 contiguous -> swizzled LDS
    {
        const unsigned short* src = Bw + (size_t)unit * 4410;
        for (int t = 0; t < 35; ++t) {
            int d = t * 64 + l;
            if (d < 2205) {
                unsigned int v2 = *(const unsigned int*)(src + 2 * d);
                int e = 2 * d;
                int part = e / 1470;
                int rem  = e - part * 1470;
                int dc   = rem / 49;
                int p    = rem - dc * 49;
#pragma unroll
                for (int half = 0; half < 2; ++half) {
                    unsigned short val = (half == 0) ? (unsigned short)(v2 & 0xffffu)
                                                     : (unsigned short)(v2 >> 16);
                    if (part < 2) {
                        int col = (((p >> 3) ^ (dc & 7)) << 3) | (p & 7);
                        U[part * 2048 + dc * 64 + col] = val;
                    } else {
                        int col = (((dc >> 3) ^ (p & 3)) << 3) | (dc & 7);
                        U[4096 + p * 32 + col] = val;
                    }
                    ++p;
                    if (p == 49) { p = 0; ++dc; if (dc == 30) { dc = 0; ++part; } }
                }
            }
        }
    }
    __syncthreads();

    s16x8 aQ[2][2], bK[2][2];
#pragma unroll
    for (int mi = 0; mi < 2; ++mi)
#pragma unroll
        for (int kk = 0; kk < 2; ++kk) {
            int r  = mi * 16 + r15;
            int gk = kk * 4 + g4;
            int so = ((gk ^ (r & 7)) << 3);
            aQ[mi][kk] = __builtin_bit_cast(s16x8, *(const u32x4*)(U + r * 64 + so));
            bK[mi][kk] = __builtin_bit_cast(s16x8, *(const u32x4*)(U + 2048 + r * 64 + so));
        }

    f32x4 s[2][2], dq[2], dk[2];
#pragma unroll
    for (int mi = 0; mi < 2; ++mi) {
        dq[mi] = (f32x4){0.f, 0.f, 0.f, 0.f};
        dk[mi] = (f32x4){0.f, 0.f, 0.f, 0.f};
#pragma unroll
        for (int nj = 0; nj < 2; ++nj) s[mi][nj] = (f32x4){0.f, 0.f, 0.f, 0.f};
    }

#pragma unroll
    for (int kk = 0; kk < 2; ++kk) {
#pragma unroll
        for (int mi = 0; mi < 2; ++mi) {
#pragma unroll
            for (int nj = 0; nj < 2; ++nj)
                s[mi][nj] = __builtin_amdgcn_mfma_f32_16x16x32_bf16(
                    aQ[mi][kk], bK[nj][kk], s[mi][nj], 0, 0, 0);
            dq[mi] = __builtin_amdgcn_mfma_f32_16x16x32_bf16(
                aQ[mi][kk], aQ[mi][kk], dq[mi], 0, 0, 0);
            dk[mi] = __builtin_amdgcn_mfma_f32_16x16x32_bf16(
                bK[mi][kk], bK[mi][kk], dk[mi], 0, 0, 0);
        }
    }

#pragma unroll
    for (int mi = 0; mi < 2; ++mi)
#pragma unroll
        for (int reg = 0; reg < 4; ++reg) {
            int row = g4 * 4 + reg;
            if (row == r15) {
                inv[mi * 16 + row]      = 1.f / fmaxf(sqrtf(dq[mi][reg]), 1e-12f);
                inv[32 + mi * 16 + row] = 1.f / fmaxf(sqrtf(dk[mi][reg]), 1e-12f);
            }
        }
    __syncthreads();

    float pr[2][2][4];
    float cinvk0 = inv[32 + r15];
    float cinvk1 = inv[32 + 16 + r15];
#pragma unroll
    for (int mi = 0; mi < 2; ++mi)
#pragma unroll
        for (int reg = 0; reg < 4; ++reg) {
            float qi = inv[mi * 16 + g4 * 4 + reg];
            float v0 = s[mi][0][reg] * qi * cinvk0 * temp;
            float v1 = s[mi][1][reg] * qi * cinvk1 * temp;
            if (16 + r15 >= 30) v1 = -1e30f;
            float m = fmaxf(v0, v1);
#pragma unroll
            for (int off = 1; off < 16; off <<= 1) m = fmaxf(m, __shfl_xor(m, off));
            float e0 = __expf(v0 - m);
            float e1 = __expf(v1 - m);
            float sum = e0 + e1;
#pragma unroll
            for (int off = 1; off < 16; off <<= 1) sum += __shfl_xor(sum, off);
            float rs = 1.f / sum;
            pr[mi][0][reg] = e0 * rs;
            pr[mi][1][reg] = e1 * rs;
        }

#pragma unroll
    for (int mi = 0; mi < 2; ++mi)
#pragma unroll
        for (int nj = 0; nj < 2; ++nj)
#pragma unroll
            for (int reg = 0; reg < 4; ++reg) {
                int row = mi * 16 + g4 * 4 + reg;
                int col = nj * 16 + r15;
                int scol = (((col >> 3) ^ (row & 3)) << 3) | (col & 7);
                U[row * 32 + scol] = f2bf(pr[mi][nj][reg]);
            }
    __syncthreads();

    s16x8 aP[2], bV[4];
#pragma unroll
    for (int mi = 0; mi < 2; ++mi) {
        int i = mi * 16 + r15;
        aP[mi] = __builtin_bit_cast(s16x8,
                 *(const u32x4*)(U + i * 32 + ((g4 ^ (i & 3)) << 3)));
    }
#pragma unroll
    for (int nt = 0; nt < 4; ++nt) {
        int p = nt * 16 + r15;
        bV[nt] = __builtin_bit_cast(s16x8,
                 *(const u32x4*)(U + 4096 + p * 32 + ((g4 ^ (p & 3)) << 3)));
    }
    f32x4 o[2][4];
#pragma unroll
    for (int mi = 0; mi < 2; ++mi)
#pragma unroll
        for (int nt = 0; nt < 4; ++nt) {
            o[mi][nt] = (f32x4){0.f, 0.f, 0.f, 0.f};
            o[mi][nt] = __builtin_amdgcn_mfma_f32_16x16x32_bf16(
                aP[mi], bV[nt], o[mi][nt], 0, 0, 0);
        }

    // store transposed: Cwt[u6][p][head*30 + ch], u32 pair stores
    unsigned short* dst = Cwt + ((size_t)u6 * 49) * 192 + head * 30;
#pragma unroll
    for (int mi = 0; mi < 2; ++mi) {
        int ch0 = mi * 16 + g4 * 4;           // 0..28 step 4
#pragma unroll
        for (int nt = 0; nt < 4; ++nt) {
            int p = nt * 16 + r15;
            if (p < 49) {
                unsigned int lo = (unsigned int)f2bf(o[mi][nt][0]) |
                                  ((unsigned int)f2bf(o[mi][nt][1]) << 16);
                *(unsigned int*)(dst + (size_t)p * 192 + ch0) = lo;
                if (ch0 + 2 < 30) {
                    unsigned int hi = (unsigned int)f2bf(o[mi][nt][2]) |
                                      ((unsigned int)f2bf(o[mi][nt][3]) << 16);
                    *(unsigned int*)(dst + (size_t)p * 192 + ch0 + 2) = hi;
                }
            }
        }
    }
    // zero-pad ch 180..191 once per (win,p)
    if (head == 5 && g4 == 0) {
        unsigned short* zrow = Cwt + ((size_t)u6 * 49) * 192 + 180;
#pragma unroll
        for (int nt = 0; nt < 4; ++nt) {
            int p = nt * 16 + r15;
            if (p < 49) {
                *(unsigned int*)(zrow + (size_t)p * 192 + 0) = 0u;
                *(unsigned int*)(zrow + (size_t)p * 192 + 2) = 0u;
                *(unsigned int*)(zrow + (size_t)p * 192 + 4) = 0u;
            }
        }
    }
}

// ---------------------------------------------------------------------------
// K4: proj GEMM via MFMA. B-op rows from Cwt [b*4096+win][49][192].
// Out: fp32 NCHW d_out with window->image scatter.
// ---------------------------------------------------------------------------
__global__ __launch_bounds__(256) void gemm_proj_kernel(
    const unsigned short* __restrict__ Cwt, const float* __restrict__ wp,
    float* __restrict__ out)
{
    const int bi   = blockIdx.z;
    const int ocb  = blockIdx.y * 64;
    const int pix0 = blockIdx.x * 256;
    const int tid  = threadIdx.x;
    const int l    = tid & 63;
    const int w    = tid >> 6;
    const int r15  = l & 15;
    const int g4   = l >> 4;

    __shared__ __align__(16) unsigned short wlds[64 * 200];
    __shared__ __align__(16) unsigned short xs[256 * 40];

    for (int idx = tid; idx < 64 * 24; idx += 256) {
        int row = idx / 24, ch = idx - (idx / 24) * 24;
        int oc = ocb + row;
        unsigned short u[8];
#pragma unroll
        for (int e = 0; e < 8; ++e) {
            int k = ch * 8 + e;
            u[e] = (oc < 180 && k < 180) ? f2bf(wp[oc * 180 + k]) : (unsigned short)0;
        }
        *(u32x4*)(wlds + row * 200 + ch * 8) = *(const u32x4*)u;
    }

    const unsigned short* srow[4];
#pragma unroll
    for (int i = 0; i < 4; ++i) {
        int P = pix0 + i * 64 + (tid >> 2);
        int win = P / 49, p = P - win * 49;
        srow[i] = Cwt + (((size_t)bi * 4096 + win) * 49 + p) * 192 + (tid & 3) * 8;
    }
    const int sdst = (tid >> 2) * 40 + (tid & 3) * 8;

    f32x4 acc[4][4];
#pragma unroll
    for (int mi = 0; mi < 4; ++mi)
#pragma unroll
        for (int nt = 0; nt < 4; ++nt) acc[mi][nt] = (f32x4){0.f, 0.f, 0.f, 0.f};

    for (int ks = 0; ks < 6; ++ks) {
        __syncthreads();
#pragma unroll
        for (int i = 0; i < 4; ++i)
            *(u32x4*)(xs + sdst + i * 64 * 40) = *(const u32x4*)(srow[i] + ks * 32);
        __syncthreads();

        s16x8 aW[4], bX[4];
#pragma unroll
        for (int mi = 0; mi < 4; ++mi)
            aW[mi] = __builtin_bit_cast(s16x8,
                     *(const u32x4*)(wlds + (mi * 16 + r15) * 200 + ks * 32 + g4 * 8));
#pragma unroll
        for (int nt = 0; nt < 4; ++nt)
            bX[nt] = __builtin_bit_cast(s16x8,
                     *(const u32x4*)(xs + (w * 64 + nt * 16 + r15) * 40 + g4 * 8));
#pragma unroll
        for (int mi = 0; mi < 4; ++mi)
#pragma unroll
            for (int nt = 0; nt < 4; ++nt)
                acc[mi][nt] = __builtin_amdgcn_mfma_f32_16x16x32_bf16(
                    aW[mi], bX[nt], acc[mi][nt], 0, 0, 0);
    }

    // window-linear pixel -> NCHW offset
    int poff[4];
#pragma unroll
    for (int nt = 0; nt < 4; ++nt) {
        int P = pix0 + w * 64 + nt * 16 + r15;
        int win = P / 49, p = P - win * 49;
        int ph = p / 7, pw2 = p - ph * 7;
        poff[nt] = ((win >> 6) * 7 + ph) * WIMG + (win & 63) * 7 + pw2;
    }
    float* ob = out + (size_t)bi * 180 * (size_t)HW;
#pragma unroll
    for (int mi = 0; mi < 4; ++mi) {
#pragma unroll
        for (int reg = 0; reg < 4; ++reg) {
            int oc = ocb + mi * 16 + g4 * 4 + reg;
            if (oc < 180) {
#pragma unroll
                for (int nt = 0; nt < 4; ++nt)
                    ob[(size_t)oc * HW + poff[nt]] = acc[mi][nt][reg];
            }
        }
    }
}

extern "C" void kernel_launch(void* const* d_in, const int* in_sizes, int n_in,
                              void* d_out, int out_size, void* d_ws, size_t ws_size,
                              hipStream_t stream) {
    const float* x           = (const float*)d_in[0];
    const float* temperature = (const float*)d_in[1];
    const float* w_qkv       = (const float*)d_in[2];
    const float* w_dw        = (const float*)d_in[3];
    const float* w_proj      = (const float*)d_in[4];
    float* out = (float*)d_out;

    const size_t R = 433520640ull;          // region size
    if (ws_size < 2 * R) return;

    // region0: xT (154MB) then Bw (433MB) ; region1: A (433MB) then Cwt (154MB)
    unsigned short* xT  = (unsigned short*)d_ws;
    unsigned short* Bw  = (unsigned short*)d_ws;
    unsigned short* A   = (unsigned short*)((char*)d_ws + R);
    unsigned short* Cwt = (unsigned short*)((char*)d_ws + R);

    transpose_cast_kernel<<<dim3(HW / 64, 2), 256, 0, stream>>>(x, xT);
    gemm_qkv_kernel<<<dim3(HW / 256, 9, 2), 256, 0, stream>>>(xT, w_qkv, A);
    dw_kernel<<<dim3(64, 540, 2), 448, 0, stream>>>(A, w_dw, Bw);
    attn2_kernel<<<dim3(12288, 1, 1), 256, 0, stream>>>(Bw, temperature, Cwt);
    gemm_proj_kernel<<<dim3(HW / 256, 3, 2), 256, 0, stream>>>(Cwt, w_proj, out);
}

// Round 4
// 1614.126 us; speedup vs baseline: 2.5648x; 1.1722x over previous
//
#include <hip/hip_runtime.h>

#define HW 200704          // 448*448
#define WIMG 448

typedef __attribute__((ext_vector_type(4))) unsigned int u32x4;
typedef __attribute__((ext_vector_type(4))) float f32x4;
typedef __attribute__((ext_vector_type(8))) short s16x8;

static __device__ __forceinline__ unsigned short f2bf(float f) {
    union { float f; unsigned int u; } v; v.f = f;
    unsigned int u = v.u;
    unsigned int r = u + 0x7FFFu + ((u >> 16) & 1u);   // RNE
    return (unsigned short)(r >> 16);
}
static __device__ __forceinline__ float bf2f(unsigned short s) {
    union { unsigned int u; float f; } v; v.u = ((unsigned int)s) << 16;
    return v.f;
}

// ---------------------------------------------------------------------------
// K0: transpose+cast  x fp32 [b][180][HW]  ->  xT bf16 [b][HW][192] (K-pad 0)
// ---------------------------------------------------------------------------
__global__ __launch_bounds__(256) void transpose_cast_kernel(
    const float* __restrict__ x, unsigned short* __restrict__ xT)
{
    const int bi = blockIdx.y;
    const int p0 = blockIdx.x * 64;
    const int tid = threadIdx.x;
    const int pl = tid & 63;

    __shared__ float T[180 * 65];

    for (int ic = tid >> 6; ic < 180; ic += 4)
        T[ic * 65 + pl] = x[((size_t)bi * 180 + ic) * HW + p0 + pl];
    __syncthreads();

    const int cg = tid >> 6;
    unsigned short* drow = xT + ((size_t)bi * HW + p0 + pl) * 192;
#pragma unroll
    for (int i = 0; i < 6; ++i) {
        int k0 = (cg * 6 + i) * 8;
        unsigned short u[8];
#pragma unroll
        for (int e = 0; e < 8; ++e)
            u[e] = (k0 + e < 180) ? f2bf(T[(k0 + e) * 65 + pl]) : (unsigned short)0;
        *(u32x4*)(drow + k0) = *(const u32x4*)u;
    }
}

// ---------------------------------------------------------------------------
// K1: qkv GEMM via MFMA.  A-op = w_qkv (bf16 in LDS), B-op = xT rows.
// Out: bf16 NCHW [b][540][HW].
// ---------------------------------------------------------------------------
__global__ __launch_bounds__(256) void gemm_qkv_kernel(
    const unsigned short* __restrict__ xT, const float* __restrict__ wq,
    unsigned short* __restrict__ A)
{
    const int bi   = blockIdx.z;
    const int ocb  = blockIdx.y * 64;
    const int pix0 = blockIdx.x * 256;
    const int tid  = threadIdx.x;
    const int l    = tid & 63;
    const int w    = tid >> 6;
    const int r15  = l & 15;
    const int g4   = l >> 4;

    __shared__ __align__(16) unsigned short wlds[64 * 200];
    __shared__ __align__(16) unsigned short xs[256 * 40];

    for (int idx = tid; idx < 64 * 24; idx += 256) {
        int row = idx / 24, ch = idx - (idx / 24) * 24;
        int oc = ocb + row;
        unsigned short u[8];
#pragma unroll
        for (int e = 0; e < 8; ++e) {
            int k = ch * 8 + e;
            u[e] = (oc < 540 && k < 180) ? f2bf(wq[oc * 180 + k]) : (unsigned short)0;
        }
        *(u32x4*)(wlds + row * 200 + ch * 8) = *(const u32x4*)u;
    }

    const unsigned short* srow[4];
#pragma unroll
    for (int i = 0; i < 4; ++i)
        srow[i] = xT + ((size_t)bi * HW + pix0 + i * 64 + (tid >> 2)) * 192 + (tid & 3) * 8;
    const int sdst = (tid >> 2) * 40 + (tid & 3) * 8;

    f32x4 acc[4][4];
#pragma unroll
    for (int mi = 0; mi < 4; ++mi)
#pragma unroll
        for (int nt = 0; nt < 4; ++nt) acc[mi][nt] = (f32x4){0.f, 0.f, 0.f, 0.f};

    for (int ks = 0; ks < 6; ++ks) {
        __syncthreads();
#pragma unroll
        for (int i = 0; i < 4; ++i)
            *(u32x4*)(xs + sdst + i * 64 * 40) = *(const u32x4*)(srow[i] + ks * 32);
        __syncthreads();

        s16x8 aW[4], bX[4];
#pragma unroll
        for (int mi = 0; mi < 4; ++mi)
            aW[mi] = __builtin_bit_cast(s16x8,
                     *(const u32x4*)(wlds + (mi * 16 + r15) * 200 + ks * 32 + g4 * 8));
#pragma unroll
        for (int nt = 0; nt < 4; ++nt)
            bX[nt] = __builtin_bit_cast(s16x8,
                     *(const u32x4*)(xs + (w * 64 + nt * 16 + r15) * 40 + g4 * 8));
#pragma unroll
        for (int mi = 0; mi < 4; ++mi)
#pragma unroll
            for (int nt = 0; nt < 4; ++nt)
                acc[mi][nt] = __builtin_amdgcn_mfma_f32_16x16x32_bf16(
                    aW[mi], bX[nt], acc[mi][nt], 0, 0, 0);
    }

#pragma unroll
    for (int mi = 0; mi < 4; ++mi) {
#pragma unroll
        for (int reg = 0; reg < 4; ++reg) {
            int oc = ocb + mi * 16 + g4 * 4 + reg;
            if (oc < 540) {
                unsigned short* orow = A + ((size_t)bi * 540 + oc) * HW + pix0 + w * 64;
#pragma unroll
                for (int nt = 0; nt < 4; ++nt)
                    orow[nt * 16 + r15] = f2bf(acc[mi][nt][reg]);
            }
        }
    }
}

// ---------------------------------------------------------------------------
// K2: depthwise 3x3 (SAME) + window rearrange, LDS-staged, fully coalesced.
// In : bf16 A [b][540][448][448]
// Out: bf16 Bw [b][head][part][dc][win][49]  (channel-plane contiguous)
// Block: (wrow, c, b), 256 threads. One 7-row strip of one channel.
// ---------------------------------------------------------------------------
__global__ __launch_bounds__(256) void dw_kernel(
    const unsigned short* __restrict__ A, const float* __restrict__ wdw,
    unsigned short* __restrict__ Bw)
{
    const int wrow = blockIdx.x;   // 0..63
    const int c    = blockIdx.y;   // 0..539
    const int b    = blockIdx.z;
    const int tid  = threadIdx.x;

    const int part = c / 180;
    const int rem  = c - part * 180;
    const int head = rem / 30;
    const int dc   = rem - head * 30;

    __shared__ float Ls[9 * 452];  // rows y0-1..y0+7, cols = image x + 1 (zero halo)

    float w9[9];
#pragma unroll
    for (int i = 0; i < 9; ++i) w9[i] = wdw[c * 9 + i];

    const int y0 = wrow * 7;
    const unsigned int* Ac32 = (const unsigned int*)(A + ((size_t)b * 540 + c) * HW);
    for (int idx = tid; idx < 2016; idx += 256) {
        int r  = idx / 224;
        int c2 = idx - r * 224;
        int y  = y0 + r - 1;
        unsigned int v = ((unsigned)y < 448u) ? Ac32[y * 224 + c2] : 0u;
        Ls[r * 452 + 1 + 2 * c2] = bf2f((unsigned short)(v & 0xffffu));
        Ls[r * 452 + 2 + 2 * c2] = bf2f((unsigned short)(v >> 16));
    }
    if (tid < 18) {
        int r = tid >> 1;
        Ls[r * 452 + ((tid & 1) ? 449 : 0)] = 0.f;
    }
    __syncthreads();

    // 3136 contiguous outputs at Bw[((b*6+head)*3+part)*30+dc][wrow*64 .. +64)[49]
    unsigned int* dst = (unsigned int*)(Bw +
        ((size_t)((b * 6 + head) * 3 + part) * 30 + dc) * 200704 + wrow * 3136);
#pragma unroll
    for (int k = 0; k < 7; ++k) {
        int o = (k * 256 + tid) * 2;
        if (o < 3136) {
            unsigned short r2[2];
#pragma unroll
            for (int e = 0; e < 2; ++e) {
                int oo = o + e;
                int wo = oo / 49;
                int rm = oo - wo * 49;
                int ph = rm / 7;
                int pw = rm - ph * 7;
                int xb = wo * 7 + pw;           // image x
                const float* L = Ls + ph * 452 + xb;
                float acc = w9[0]*L[0] + w9[1]*L[1] + w9[2]*L[2];
                L += 452;
                acc += w9[3]*L[0] + w9[4]*L[1] + w9[5]*L[2];
                L += 452;
                acc += w9[6]*L[0] + w9[7]*L[1] + w9[8]*L[2];
                r2[e] = f2bf(acc);
            }
            dst[o >> 1] = (unsigned int)r2[0] | ((unsigned int)r2[1] << 16);
        }
    }
}

// ---------------------------------------------------------------------------
// K3: per-(b,win,head) channel attention. Block = 4 consecutive windows of one
// (b, head); cooperative staging from channel-plane Bw (392-B runs).
// Out: Cwt [b*4096+win][49][192] bf16 (K-pad 180..191 zeroed by head==5)
// ---------------------------------------------------------------------------
__global__ __launch_bounds__(256) void attn2_kernel(
    const unsigned short* __restrict__ Bw,
    const float* __restrict__ temperature,
    unsigned short* __restrict__ Cwt)
{
    __shared__ __align__(16) unsigned short lds[4][6144];
    __shared__ float invs[4][64];

    const int w    = threadIdx.x >> 6;
    const int l    = threadIdx.x & 63;
    const int wg   = blockIdx.x;          // win-group of 4
    const int head = blockIdx.y;
    const int b    = blockIdx.z;
    const int win  = wg * 4 + w;
    const int u6   = b * 4096 + win;
    const float temp = temperature[head];
    unsigned short* U = lds[w];
    float* inv = invs[w];
    const int r15 = l & 15;
    const int g4  = l >> 4;

    // zero LDS (padding rows/cols must be 0)
    {
        const u32x4 vz = {0u, 0u, 0u, 0u};
        u32x4* Z = (u32x4*)U;
#pragma unroll
        for (int i = 0; i < 12; ++i) Z[i * 64 + l] = vz;
    }
    __syncthreads();

    // cooperative stage: 90 runs (part,dc) x 196 u16 (4 windows x 49) -> swizzled LDS
    {
        const unsigned short* srcbase =
            Bw + (size_t)((b * 6 + head) * 3) * 30 * 200704 + (size_t)wg * 196;
        for (int t = 0; t < 35; ++t) {
            int idx = t * 256 + threadIdx.x;
            if (idx < 8820) {
                int r = idx / 98;
                int j = idx - r * 98;
                unsigned int v2 = *(const unsigned int*)(srcbase + (size_t)r * 200704 + 2 * j);
                int part = r / 30;
                int dc   = r - part * 30;
                int e    = 2 * j;
#pragma unroll
                for (int half = 0; half < 2; ++half) {
                    unsigned short val = half ? (unsigned short)(v2 >> 16)
                                              : (unsigned short)(v2 & 0xffffu);
                    int wo = e / 49;
                    int p  = e - wo * 49;
                    unsigned short* Uw = lds[wo];
                    if (part < 2) {
                        int col = (((p >> 3) ^ (dc & 7)) << 3) | (p & 7);
                        Uw[part * 2048 + dc * 64 + col] = val;
                    } else {
                        int col = (((dc >> 3) ^ (p & 3)) << 3) | (dc & 7);
                        Uw[4096 + p * 32 + col] = val;
                    }
                    ++e;
                }
            }
        }
    }
    __syncthreads();

    s16x8 aQ[2][2], bK[2][2];
#pragma unroll
    for (int mi = 0; mi < 2; ++mi)
#pragma unroll
        for (int kk = 0; kk < 2; ++kk) {
            int r  = mi * 16 + r15;
            int gk = kk * 4 + g4;
            int so = ((gk ^ (r & 7)) << 3);
            aQ[mi][kk] = __builtin_bit_cast(s16x8, *(const u32x4*)(U + r * 64 + so));
            bK[mi][kk] = __builtin_bit_cast(s16x8, *(const u32x4*)(U + 2048 + r * 64 + so));
        }

    f32x4 s[2][2], dq[2], dk[2];
#pragma unroll
    for (int mi = 0; mi < 2; ++mi) {
        dq[mi] = (f32x4){0.f, 0.f, 0.f, 0.f};
        dk[mi] = (f32x4){0.f, 0.f, 0.f, 0.f};
#pragma unroll
        for (int nj = 0; nj < 2; ++nj) s[mi][nj] = (f32x4){0.f, 0.f, 0.f, 0.f};
    }

#pragma unroll
    for (int kk = 0; kk < 2; ++kk) {
#pragma unroll
        for (int mi = 0; mi < 2; ++mi) {
#pragma unroll
            for (int nj = 0; nj < 2; ++nj)
                s[mi][nj] = __builtin_amdgcn_mfma_f32_16x16x32_bf16(
                    aQ[mi][kk], bK[nj][kk], s[mi][nj], 0, 0, 0);
            dq[mi] = __builtin_amdgcn_mfma_f32_16x16x32_bf16(
                aQ[mi][kk], aQ[mi][kk], dq[mi], 0, 0, 0);
            dk[mi] = __builtin_amdgcn_mfma_f32_16x16x32_bf16(
                bK[mi][kk], bK[mi][kk], dk[mi], 0, 0, 0);
        }
    }

#pragma unroll
    for (int mi = 0; mi < 2; ++mi)
#pragma unroll
        for (int reg = 0; reg < 4; ++reg) {
            int row = g4 * 4 + reg;
            if (row == r15) {
                inv[mi * 16 + row]      = 1.f / fmaxf(sqrtf(dq[mi][reg]), 1e-12f);
                inv[32 + mi * 16 + row] = 1.f / fmaxf(sqrtf(dk[mi][reg]), 1e-12f);
            }
        }
    __syncthreads();

    float pr[2][2][4];
    float cinvk0 = inv[32 + r15];
    float cinvk1 = inv[32 + 16 + r15];
#pragma unroll
    for (int mi = 0; mi < 2; ++mi)
#pragma unroll
        for (int reg = 0; reg < 4; ++reg) {
            float qi = inv[mi * 16 + g4 * 4 + reg];
            float v0 = s[mi][0][reg] * qi * cinvk0 * temp;
            float v1 = s[mi][1][reg] * qi * cinvk1 * temp;
            if (16 + r15 >= 30) v1 = -1e30f;
            float m = fmaxf(v0, v1);
#pragma unroll
            for (int off = 1; off < 16; off <<= 1) m = fmaxf(m, __shfl_xor(m, off));
            float e0 = __expf(v0 - m);
            float e1 = __expf(v1 - m);
            float sum = e0 + e1;
#pragma unroll
            for (int off = 1; off < 16; off <<= 1) sum += __shfl_xor(sum, off);
            float rs = 1.f / sum;
            pr[mi][0][reg] = e0 * rs;
            pr[mi][1][reg] = e1 * rs;
        }

#pragma unroll
    for (int mi = 0; mi < 2; ++mi)
#pragma unroll
        for (int nj = 0; nj < 2; ++nj)
#pragma unroll
            for (int reg = 0; reg < 4; ++reg) {
                int row = mi * 16 + g4 * 4 + reg;
                int col = nj * 16 + r15;
                int scol = (((col >> 3) ^ (row & 3)) << 3) | (col & 7);
                U[row * 32 + scol] = f2bf(pr[mi][nj][reg]);
            }
    __syncthreads();

    s16x8 aP[2], bV[4];
#pragma unroll
    for (int mi = 0; mi < 2; ++mi) {
        int i = mi * 16 + r15;
        aP[mi] = __builtin_bit_cast(s16x8,
                 *(const u32x4*)(U + i * 32 + ((g4 ^ (i & 3)) << 3)));
    }
#pragma unroll
    for (int nt = 0; nt < 4; ++nt) {
        int p = nt * 16 + r15;
        bV[nt] = __builtin_bit_cast(s16x8,
                 *(const u32x4*)(U + 4096 + p * 32 + ((g4 ^ (p & 3)) << 3)));
    }
    f32x4 o[2][4];
#pragma unroll
    for (int mi = 0; mi < 2; ++mi)
#pragma unroll
        for (int nt = 0; nt < 4; ++nt) {
            o[mi][nt] = (f32x4){0.f, 0.f, 0.f, 0.f};
            o[mi][nt] = __builtin_amdgcn_mfma_f32_16x16x32_bf16(
                aP[mi], bV[nt], o[mi][nt], 0, 0, 0);
        }

    unsigned short* dst = Cwt + ((size_t)u6 * 49) * 192 + head * 30;
#pragma unroll
    for (int mi = 0; mi < 2; ++mi) {
        int ch0 = mi * 16 + g4 * 4;
#pragma unroll
        for (int nt = 0; nt < 4; ++nt) {
            int p = nt * 16 + r15;
            if (p < 49) {
                unsigned int lo = (unsigned int)f2bf(o[mi][nt][0]) |
                                  ((unsigned int)f2bf(o[mi][nt][1]) << 16);
                *(unsigned int*)(dst + (size_t)p * 192 + ch0) = lo;
                if (ch0 + 2 < 30) {
                    unsigned int hi = (unsigned int)f2bf(o[mi][nt][2]) |
                                      ((unsigned int)f2bf(o[mi][nt][3]) << 16);
                    *(unsigned int*)(dst + (size_t)p * 192 + ch0 + 2) = hi;
                }
            }
        }
    }
    if (head == 5 && g4 == 0) {
        unsigned short* zrow = Cwt + ((size_t)u6 * 49) * 192 + 180;
#pragma unroll
        for (int nt = 0; nt < 4; ++nt) {
            int p = nt * 16 + r15;
            if (p < 49) {
                *(unsigned int*)(zrow + (size_t)p * 192 + 0) = 0u;
                *(unsigned int*)(zrow + (size_t)p * 192 + 2) = 0u;
                *(unsigned int*)(zrow + (size_t)p * 192 + 4) = 0u;
            }
        }
    }
}

// ---------------------------------------------------------------------------
// K4: proj GEMM via MFMA. B-op rows from Cwt [b*4096+win][49][192].
// Out: fp32 NCHW d_out with window->image scatter.
// ---------------------------------------------------------------------------
__global__ __launch_bounds__(256) void gemm_proj_kernel(
    const unsigned short* __restrict__ Cwt, const float* __restrict__ wp,
    float* __restrict__ out)
{
    const int bi   = blockIdx.z;
    const int ocb  = blockIdx.y * 64;
    const int pix0 = blockIdx.x * 256;
    const int tid  = threadIdx.x;
    const int l    = tid & 63;
    const int w    = tid >> 6;
    const int r15  = l & 15;
    const int g4   = l >> 4;

    __shared__ __align__(16) unsigned short wlds[64 * 200];
    __shared__ __align__(16) unsigned short xs[256 * 40];

    for (int idx = tid; idx < 64 * 24; idx += 256) {
        int row = idx / 24, ch = idx - (idx / 24) * 24;
        int oc = ocb + row;
        unsigned short u[8];
#pragma unroll
        for (int e = 0; e < 8; ++e) {
            int k = ch * 8 + e;
            u[e] = (oc < 180 && k < 180) ? f2bf(wp[oc * 180 + k]) : (unsigned short)0;
        }
        *(u32x4*)(wlds + row * 200 + ch * 8) = *(const u32x4*)u;
    }

    const unsigned short* srow[4];
#pragma unroll
    for (int i = 0; i < 4; ++i) {
        int P = pix0 + i * 64 + (tid >> 2);
        int win = P / 49, p = P - win * 49;
        srow[i] = Cwt + (((size_t)bi * 4096 + win) * 49 + p) * 192 + (tid & 3) * 8;
    }
    const int sdst = (tid >> 2) * 40 + (tid & 3) * 8;

    f32x4 acc[4][4];
#pragma unroll
    for (int mi = 0; mi < 4; ++mi)
#pragma unroll
        for (int nt = 0; nt < 4; ++nt) acc[mi][nt] = (f32x4){0.f, 0.f, 0.f, 0.f};

    for (int ks = 0; ks < 6; ++ks) {
        __syncthreads();
#pragma unroll
        for (int i = 0; i < 4; ++i)
            *(u32x4*)(xs + sdst + i * 64 * 40) = *(const u32x4*)(srow[i] + ks * 32);
        __syncthreads();

        s16x8 aW[4], bX[4];
#pragma unroll
        for (int mi = 0; mi < 4; ++mi)
            aW[mi] = __builtin_bit_cast(s16x8,
                     *(const u32x4*)(wlds + (mi * 16 + r15) * 200 + ks * 32 + g4 * 8));
#pragma unroll
        for (int nt = 0; nt < 4; ++nt)
            bX[nt] = __builtin_bit_cast(s16x8,
                     *(const u32x4*)(xs + (w * 64 + nt * 16 + r15) * 40 + g4 * 8));
#pragma unroll
        for (int mi = 0; mi < 4; ++mi)
#pragma unroll
            for (int nt = 0; nt < 4; ++nt)
                acc[mi][nt] = __builtin_amdgcn_mfma_f32_16x16x32_bf16(
                    aW[mi], bX[nt], acc[mi][nt], 0, 0, 0);
    }

    int poff[4];
#pragma unroll
    for (int nt = 0; nt < 4; ++nt) {
        int P = pix0 + w * 64 + nt * 16 + r15;
        int win = P / 49, p = P - win * 49;
        int ph = p / 7, pw2 = p - ph * 7;
        poff[nt] = ((win >> 6) * 7 + ph) * WIMG + (win & 63) * 7 + pw2;
    }
    float* ob = out + (size_t)bi * 180 * (size_t)HW;
#pragma unroll
    for (int mi = 0; mi < 4; ++mi) {
#pragma unroll
        for (int reg = 0; reg < 4; ++reg) {
            int oc = ocb + mi * 16 + g4 * 4 + reg;
            if (oc < 180) {
#pragma unroll
                for (int nt = 0; nt < 4; ++nt)
                    ob[(size_t)oc * HW + poff[nt]] = acc[mi][nt][reg];
            }
        }
    }
}

extern "C" void kernel_launch(void* const* d_in, const int* in_sizes, int n_in,
                              void* d_out, int out_size, void* d_ws, size_t ws_size,
                              hipStream_t stream) {
    const float* x           = (const float*)d_in[0];
    const float* temperature = (const float*)d_in[1];
    const float* w_qkv       = (const float*)d_in[2];
    const float* w_dw        = (const float*)d_in[3];
    const float* w_proj      = (const float*)d_in[4];
    float* out = (float*)d_out;

    const size_t R = 433520640ull;          // region size
    if (ws_size < 2 * R) return;

    // region0: xT (154MB) then Bw (433MB) ; region1: A (433MB) then Cwt (154MB)
    unsigned short* xT  = (unsigned short*)d_ws;
    unsigned short* Bw  = (unsigned short*)d_ws;
    unsigned short* A   = (unsigned short*)((char*)d_ws + R);
    unsigned short* Cwt = (unsigned short*)((char*)d_ws + R);

    transpose_cast_kernel<<<dim3(HW / 64, 2), 256, 0, stream>>>(x, xT);
    gemm_qkv_kernel<<<dim3(HW / 256, 9, 2), 256, 0, stream>>>(xT, w_qkv, A);
    dw_kernel<<<dim3(64, 540, 2), 256, 0, stream>>>(A, w_dw, Bw);
    attn2_kernel<<<dim3(1024, 6, 2), 256, 0, stream>>>(Bw, temperature, Cwt);
    gemm_proj_kernel<<<dim3(HW / 256, 3, 2), 256, 0, stream>>>(Cwt, w_proj, out);
}

// Round 5
// 1483.996 us; speedup vs baseline: 2.7897x; 1.0877x over previous
//
#include <hip/hip_runtime.h>

#define HW 200704          // 448*448
#define WIMG 448
#define VPLANE 229376      // 4096 windows * 56 padded pixels (u16 elements)

typedef __attribute__((ext_vector_type(4))) unsigned int u32x4;
typedef __attribute__((ext_vector_type(4))) float f32x4;
typedef __attribute__((ext_vector_type(8))) short s16x8;

static __device__ __forceinline__ unsigned short f2bf(float f) {
    union { float f; unsigned int u; } v; v.f = f;
    unsigned int u = v.u;
    unsigned int r = u + 0x7FFFu + ((u >> 16) & 1u);   // RNE
    return (unsigned short)(r >> 16);
}
static __device__ __forceinline__ float bf2f(unsigned short s) {
    union { unsigned int u; float f; } v; v.u = ((unsigned int)s) << 16;
    return v.f;
}

// ---------------------------------------------------------------------------
// K0: transpose+cast  x fp32 [180][HW] -> xT bf16 [HW][192] (one batch)
// ---------------------------------------------------------------------------
__global__ __launch_bounds__(256) void transpose_cast_kernel(
    const float* __restrict__ x, unsigned short* __restrict__ xT)
{
    const int p0 = blockIdx.x * 64;
    const int tid = threadIdx.x;
    const int pl = tid & 63;

    __shared__ float T[180 * 65];

    for (int ic = tid >> 6; ic < 180; ic += 4)
        T[ic * 65 + pl] = x[(size_t)ic * HW + p0 + pl];
    __syncthreads();

    const int cg = tid >> 6;
    unsigned short* drow = xT + ((size_t)p0 + pl) * 192;
#pragma unroll
    for (int i = 0; i < 6; ++i) {
        int k0 = (cg * 6 + i) * 8;
        unsigned short u[8];
#pragma unroll
        for (int e = 0; e < 8; ++e)
            u[e] = (k0 + e < 180) ? f2bf(T[(k0 + e) * 65 + pl]) : (unsigned short)0;
        *(u32x4*)(drow + k0) = *(const u32x4*)u;
    }
}

// ---------------------------------------------------------------------------
// K1: qkv GEMM via MFMA (one batch). Out: bf16 NCHW [540][HW].
// ---------------------------------------------------------------------------
__global__ __launch_bounds__(256) void gemm_qkv_kernel(
    const unsigned short* __restrict__ xT, const float* __restrict__ wq,
    unsigned short* __restrict__ A)
{
    const int ocb  = blockIdx.y * 64;
    const int pix0 = blockIdx.x * 256;
    const int tid  = threadIdx.x;
    const int l    = tid & 63;
    const int w    = tid >> 6;
    const int r15  = l & 15;
    const int g4   = l >> 4;

    __shared__ __align__(16) unsigned short wlds[64 * 200];
    __shared__ __align__(16) unsigned short xs[256 * 40];

    for (int idx = tid; idx < 64 * 24; idx += 256) {
        int row = idx / 24, ch = idx - (idx / 24) * 24;
        int oc = ocb + row;
        unsigned short u[8];
#pragma unroll
        for (int e = 0; e < 8; ++e) {
            int k = ch * 8 + e;
            u[e] = (oc < 540 && k < 180) ? f2bf(wq[oc * 180 + k]) : (unsigned short)0;
        }
        *(u32x4*)(wlds + row * 200 + ch * 8) = *(const u32x4*)u;
    }

    const unsigned short* srow[4];
#pragma unroll
    for (int i = 0; i < 4; ++i)
        srow[i] = xT + ((size_t)pix0 + i * 64 + (tid >> 2)) * 192 + (tid & 3) * 8;
    const int sdst = (tid >> 2) * 40 + (tid & 3) * 8;

    f32x4 acc[4][4];
#pragma unroll
    for (int mi = 0; mi < 4; ++mi)
#pragma unroll
        for (int nt = 0; nt < 4; ++nt) acc[mi][nt] = (f32x4){0.f, 0.f, 0.f, 0.f};

    for (int ks = 0; ks < 6; ++ks) {
        __syncthreads();
#pragma unroll
        for (int i = 0; i < 4; ++i)
            *(u32x4*)(xs + sdst + i * 64 * 40) = *(const u32x4*)(srow[i] + ks * 32);
        __syncthreads();

        s16x8 aW[4], bX[4];
#pragma unroll
        for (int mi = 0; mi < 4; ++mi)
            aW[mi] = __builtin_bit_cast(s16x8,
                     *(const u32x4*)(wlds + (mi * 16 + r15) * 200 + ks * 32 + g4 * 8));
#pragma unroll
        for (int nt = 0; nt < 4; ++nt)
            bX[nt] = __builtin_bit_cast(s16x8,
                     *(const u32x4*)(xs + (w * 64 + nt * 16 + r15) * 40 + g4 * 8));
#pragma unroll
        for (int mi = 0; mi < 4; ++mi)
#pragma unroll
            for (int nt = 0; nt < 4; ++nt)
                acc[mi][nt] = __builtin_amdgcn_mfma_f32_16x16x32_bf16(
                    aW[mi], bX[nt], acc[mi][nt], 0, 0, 0);
    }

#pragma unroll
    for (int mi = 0; mi < 4; ++mi) {
#pragma unroll
        for (int reg = 0; reg < 4; ++reg) {
            int oc = ocb + mi * 16 + g4 * 4 + reg;
            if (oc < 540) {
                unsigned short* orow = A + (size_t)oc * HW + pix0 + w * 64;
#pragma unroll
                for (int nt = 0; nt < 4; ++nt)
                    orow[nt * 16 + r15] = f2bf(acc[mi][nt][reg]);
            }
        }
    }
}

// ---------------------------------------------------------------------------
// K2: depthwise 3x3 (SAME) + window rearrange (one batch).
// In : bf16 A [540][448][448]
// Out: bf16 Bw [head][part][dc][win][56]  (p 49..55 zero)
// Block: (wrow, c), 256 threads. One 7-row strip of one channel.
// ---------------------------------------------------------------------------
__global__ __launch_bounds__(256) void dw_kernel(
    const unsigned short* __restrict__ A, const float* __restrict__ wdw,
    unsigned short* __restrict__ Bw)
{
    const int wrow = blockIdx.x;   // 0..63
    const int c    = blockIdx.y;   // 0..539
    const int tid  = threadIdx.x;

    const int part = c / 180;
    const int rem  = c - part * 180;
    const int head = rem / 30;
    const int dc   = rem - head * 30;

    __shared__ float Ls[9 * 452];

    float w9[9];
#pragma unroll
    for (int i = 0; i < 9; ++i) w9[i] = wdw[c * 9 + i];

    const int y0 = wrow * 7;
    const unsigned int* Ac32 = (const unsigned int*)(A + (size_t)c * HW);
    for (int idx = tid; idx < 2016; idx += 256) {
        int r  = idx / 224;
        int c2 = idx - r * 224;
        int y  = y0 + r - 1;
        unsigned int v = ((unsigned)y < 448u) ? Ac32[y * 224 + c2] : 0u;
        Ls[r * 452 + 1 + 2 * c2] = bf2f((unsigned short)(v & 0xffffu));
        Ls[r * 452 + 2 + 2 * c2] = bf2f((unsigned short)(v >> 16));
    }
    if (tid < 18) {
        int r = tid >> 1;
        Ls[r * 452 + ((tid & 1) ? 449 : 0)] = 0.f;
    }
    __syncthreads();

    // 3584 u16 (1792 u32) contiguous: windows wrow*64..+63, 56 each (7 pad zeros)
    unsigned int* dst = (unsigned int*)(Bw +
        ((size_t)(head * 3 + part) * 30 + dc) * VPLANE + (size_t)wrow * 64 * 56);
#pragma unroll
    for (int k = 0; k < 7; ++k) {
        int o2 = k * 256 + tid;            // u32 index 0..1791
        int wo = o2 / 28;                  // window in strip
        int r2 = o2 - wo * 28;             // u32 within window (28 = 56/2)
        unsigned short r2v[2];
#pragma unroll
        for (int e = 0; e < 2; ++e) {
            int rm = r2 * 2 + e;
            float acc = 0.f;
            if (rm < 49) {
                int ph = rm / 7, pw = rm - ph * 7;
                int xb = wo * 7 + pw;
                const float* L = Ls + ph * 452 + xb;
                acc = w9[0]*L[0] + w9[1]*L[1] + w9[2]*L[2];
                L += 452;
                acc += w9[3]*L[0] + w9[4]*L[1] + w9[5]*L[2];
                L += 452;
                acc += w9[6]*L[0] + w9[7]*L[1] + w9[8]*L[2];
            }
            r2v[e] = (rm < 49) ? f2bf(acc) : (unsigned short)0;
        }
        dst[o2] = (unsigned int)r2v[0] | ((unsigned int)r2v[1] << 16);
    }
}

// ---------------------------------------------------------------------------
// K3: channel attention (one batch). Block = 4 consecutive windows of one head,
// one wave each. Vectorized b128 staging for Q/K; per-element transpose for V.
// Out: Cwt [win][49][192] bf16 (ch 180..191 zeroed by head==5)
// ---------------------------------------------------------------------------
__global__ __launch_bounds__(256) void attn2_kernel(
    const unsigned short* __restrict__ Bw,
    const float* __restrict__ temperature,
    unsigned short* __restrict__ Cwt)
{
    __shared__ __align__(16) unsigned short lds[4][6144];
    __shared__ float invs[4][64];

    const int w    = threadIdx.x >> 6;
    const int l    = threadIdx.x & 63;
    const int wg   = blockIdx.x;
    const int head = blockIdx.y;
    const int win  = wg * 4 + w;
    const float temp = temperature[head];
    unsigned short* U = lds[w];
    float* inv = invs[w];
    const int r15 = l & 15;
    const int g4  = l >> 4;

    // ---- stage Q/K: 8 b128 per lane (rows>=30 and chunk 7 -> zeros) ----
    {
        const unsigned short* plane0 =
            Bw + (size_t)(head * 3) * 30 * VPLANE + (size_t)win * 56;
#pragma unroll
        for (int i = 0; i < 8; ++i) {
            int part = i >> 2;
            int row  = ((i & 3) << 3) | (l >> 3);   // 0..31
            int c    = l & 7;
            u32x4 v = {0u, 0u, 0u, 0u};
            if (row < 30 && c < 7)
                v = *(const u32x4*)(plane0 + (size_t)(part * 30 + row) * VPLANE + c * 8);
            *(u32x4*)(U + part * 2048 + row * 64 + ((c ^ (row & 7)) << 3)) = v;
        }
    }
    // ---- stage V transposed into Vt [p][32] (swizzled), zero cols 30/31 ----
    {
        const unsigned short* vplane =
            Bw + (size_t)(head * 3 + 2) * 30 * VPLANE + (size_t)win * 56;
        for (int j = 0; j < 23; ++j) {
            int idx = j * 64 + l;
            if (idx < 1470) {
                int dc = idx / 49;
                int p  = idx - dc * 49;
                unsigned short val = vplane[(size_t)dc * VPLANE + p];
                int col = (((dc >> 3) ^ (p & 3)) << 3) | (dc & 7);
                U[4096 + p * 32 + col] = val;
            }
        }
        int c30 = ((3 ^ (l & 3)) << 3) | 6;         // dc=30 slot for p=l
        U[4096 + l * 32 + c30]     = 0;
        U[4096 + l * 32 + c30 + 1] = 0;             // dc=31
    }
    __syncthreads();

    s16x8 aQ[2][2], bK[2][2];
#pragma unroll
    for (int mi = 0; mi < 2; ++mi)
#pragma unroll
        for (int kk = 0; kk < 2; ++kk) {
            int r  = mi * 16 + r15;
            int gk = kk * 4 + g4;
            int so = ((gk ^ (r & 7)) << 3);
            aQ[mi][kk] = __builtin_bit_cast(s16x8, *(const u32x4*)(U + r * 64 + so));
            bK[mi][kk] = __builtin_bit_cast(s16x8, *(const u32x4*)(U + 2048 + r * 64 + so));
        }

    f32x4 s[2][2], dq[2], dk[2];
#pragma unroll
    for (int mi = 0; mi < 2; ++mi) {
        dq[mi] = (f32x4){0.f, 0.f, 0.f, 0.f};
        dk[mi] = (f32x4){0.f, 0.f, 0.f, 0.f};
#pragma unroll
        for (int nj = 0; nj < 2; ++nj) s[mi][nj] = (f32x4){0.f, 0.f, 0.f, 0.f};
    }

#pragma unroll
    for (int kk = 0; kk < 2; ++kk) {
#pragma unroll
        for (int mi = 0; mi < 2; ++mi) {
#pragma unroll
            for (int nj = 0; nj < 2; ++nj)
                s[mi][nj] = __builtin_amdgcn_mfma_f32_16x16x32_bf16(
                    aQ[mi][kk], bK[nj][kk], s[mi][nj], 0, 0, 0);
            dq[mi] = __builtin_amdgcn_mfma_f32_16x16x32_bf16(
                aQ[mi][kk], aQ[mi][kk], dq[mi], 0, 0, 0);
            dk[mi] = __builtin_amdgcn_mfma_f32_16x16x32_bf16(
                bK[mi][kk], bK[mi][kk], dk[mi], 0, 0, 0);
        }
    }

#pragma unroll
    for (int mi = 0; mi < 2; ++mi)
#pragma unroll
        for (int reg = 0; reg < 4; ++reg) {
            int row = g4 * 4 + reg;
            if (row == r15) {
                inv[mi * 16 + row]      = 1.f / fmaxf(sqrtf(dq[mi][reg]), 1e-12f);
                inv[32 + mi * 16 + row] = 1.f / fmaxf(sqrtf(dk[mi][reg]), 1e-12f);
            }
        }
    __syncthreads();

    float pr[2][2][4];
    float cinvk0 = inv[32 + r15];
    float cinvk1 = inv[32 + 16 + r15];
#pragma unroll
    for (int mi = 0; mi < 2; ++mi)
#pragma unroll
        for (int reg = 0; reg < 4; ++reg) {
            float qi = inv[mi * 16 + g4 * 4 + reg];
            float v0 = s[mi][0][reg] * qi * cinvk0 * temp;
            float v1 = s[mi][1][reg] * qi * cinvk1 * temp;
            if (16 + r15 >= 30) v1 = -1e30f;
            float m = fmaxf(v0, v1);
#pragma unroll
            for (int off = 1; off < 16; off <<= 1) m = fmaxf(m, __shfl_xor(m, off));
            float e0 = __expf(v0 - m);
            float e1 = __expf(v1 - m);
            float sum = e0 + e1;
#pragma unroll
            for (int off = 1; off < 16; off <<= 1) sum += __shfl_xor(sum, off);
            float rs = 1.f / sum;
            pr[mi][0][reg] = e0 * rs;
            pr[mi][1][reg] = e1 * rs;
        }

#pragma unroll
    for (int mi = 0; mi < 2; ++mi)
#pragma unroll
        for (int nj = 0; nj < 2; ++nj)
#pragma unroll
            for (int reg = 0; reg < 4; ++reg) {
                int row = mi * 16 + g4 * 4 + reg;
                int col = nj * 16 + r15;
                int scol = (((col >> 3) ^ (row & 3)) << 3) | (col & 7);
                U[row * 32 + scol] = f2bf(pr[mi][nj][reg]);
            }
    __syncthreads();

    s16x8 aP[2], bV[4];
#pragma unroll
    for (int mi = 0; mi < 2; ++mi) {
        int i = mi * 16 + r15;
        aP[mi] = __builtin_bit_cast(s16x8,
                 *(const u32x4*)(U + i * 32 + ((g4 ^ (i & 3)) << 3)));
    }
#pragma unroll
    for (int nt = 0; nt < 4; ++nt) {
        int p = nt * 16 + r15;
        bV[nt] = __builtin_bit_cast(s16x8,
                 *(const u32x4*)(U + 4096 + p * 32 + ((g4 ^ (p & 3)) << 3)));
    }
    f32x4 o[2][4];
#pragma unroll
    for (int mi = 0; mi < 2; ++mi)
#pragma unroll
        for (int nt = 0; nt < 4; ++nt) {
            o[mi][nt] = (f32x4){0.f, 0.f, 0.f, 0.f};
            o[mi][nt] = __builtin_amdgcn_mfma_f32_16x16x32_bf16(
                aP[mi], bV[nt], o[mi][nt], 0, 0, 0);
        }

    unsigned short* dst = Cwt + ((size_t)win * 49) * 192 + head * 30;
#pragma unroll
    for (int mi = 0; mi < 2; ++mi) {
        int ch0 = mi * 16 + g4 * 4;
#pragma unroll
        for (int nt = 0; nt < 4; ++nt) {
            int p = nt * 16 + r15;
            if (p < 49) {
                unsigned int lo = (unsigned int)f2bf(o[mi][nt][0]) |
                                  ((unsigned int)f2bf(o[mi][nt][1]) << 16);
                *(unsigned int*)(dst + (size_t)p * 192 + ch0) = lo;
                if (ch0 + 2 < 30) {
                    unsigned int hi = (unsigned int)f2bf(o[mi][nt][2]) |
                                      ((unsigned int)f2bf(o[mi][nt][3]) << 16);
                    *(unsigned int*)(dst + (size_t)p * 192 + ch0 + 2) = hi;
                }
            }
        }
    }
    if (head == 5 && g4 == 0) {
        unsigned short* zrow = Cwt + ((size_t)win * 49) * 192 + 180;
#pragma unroll
        for (int nt = 0; nt < 4; ++nt) {
            int p = nt * 16 + r15;
            if (p < 49) {
                *(unsigned int*)(zrow + (size_t)p * 192 + 0) = 0u;
                *(unsigned int*)(zrow + (size_t)p * 192 + 2) = 0u;
                *(unsigned int*)(zrow + (size_t)p * 192 + 4) = 0u;
            }
        }
    }
}

// ---------------------------------------------------------------------------
// K4: proj GEMM via MFMA (one batch). B-op rows from Cwt [win][49][192].
// Out: fp32 NCHW with window->image scatter.
// ---------------------------------------------------------------------------
__global__ __launch_bounds__(256) void gemm_proj_kernel(
    const unsigned short* __restrict__ Cwt, const float* __restrict__ wp,
    float* __restrict__ out)
{
    const int ocb  = blockIdx.y * 64;
    const int pix0 = blockIdx.x * 256;
    const int tid  = threadIdx.x;
    const int l    = tid & 63;
    const int w    = tid >> 6;
    const int r15  = l & 15;
    const int g4   = l >> 4;

    __shared__ __align__(16) unsigned short wlds[64 * 200];
    __shared__ __align__(16) unsigned short xs[256 * 40];

    for (int idx = tid; idx < 64 * 24; idx += 256) {
        int row = idx / 24, ch = idx - (idx / 24) * 24;
        int oc = ocb + row;
        unsigned short u[8];
#pragma unroll
        for (int e = 0; e < 8; ++e) {
            int k = ch * 8 + e;
            u[e] = (oc < 180 && k < 180) ? f2bf(wp[oc * 180 + k]) : (unsigned short)0;
        }
        *(u32x4*)(wlds + row * 200 + ch * 8) = *(const u32x4*)u;
    }

    const unsigned short* srow[4];
#pragma unroll
    for (int i = 0; i < 4; ++i) {
        int P = pix0 + i * 64 + (tid >> 2);
        int win = P / 49, p = P - win * 49;
        srow[i] = Cwt + ((size_t)win * 49 + p) * 192 + (tid & 3) * 8;
    }
    const int sdst = (tid >> 2) * 40 + (tid & 3) * 8;

    f32x4 acc[4][4];
#pragma unroll
    for (int mi = 0; mi < 4; ++mi)
#pragma unroll
        for (int nt = 0; nt < 4; ++nt) acc[mi][nt] = (f32x4){0.f, 0.f, 0.f, 0.f};

    for (int ks = 0; ks < 6; ++ks) {
        __syncthreads();
#pragma unroll
        for (int i = 0; i < 4; ++i)
            *(u32x4*)(xs + sdst + i * 64 * 40) = *(const u32x4*)(srow[i] + ks * 32);
        __syncthreads();

        s16x8 aW[4], bX[4];
#pragma unroll
        for (int mi = 0; mi < 4; ++mi)
            aW[mi] = __builtin_bit_cast(s16x8,
                     *(const u32x4*)(wlds + (mi * 16 + r15) * 200 + ks * 32 + g4 * 8));
#pragma unroll
        for (int nt = 0; nt < 4; ++nt)
            bX[nt] = __builtin_bit_cast(s16x8,
                     *(const u32x4*)(xs + (w * 64 + nt * 16 + r15) * 40 + g4 * 8));
#pragma unroll
        for (int mi = 0; mi < 4; ++mi)
#pragma unroll
            for (int nt = 0; nt < 4; ++nt)
                acc[mi][nt] = __builtin_amdgcn_mfma_f32_16x16x32_bf16(
                    aW[mi], bX[nt], acc[mi][nt], 0, 0, 0);
    }

    int poff[4];
#pragma unroll
    for (int nt = 0; nt < 4; ++nt) {
        int P = pix0 + w * 64 + nt * 16 + r15;
        int win = P / 49, p = P - win * 49;
        int ph = p / 7, pw2 = p - ph * 7;
        poff[nt] = ((win >> 6) * 7 + ph) * WIMG + (win & 63) * 7 + pw2;
    }
#pragma unroll
    for (int mi = 0; mi < 4; ++mi) {
#pragma unroll
        for (int reg = 0; reg < 4; ++reg) {
            int oc = ocb + mi * 16 + g4 * 4 + reg;
            if (oc < 180) {
#pragma unroll
                for (int nt = 0; nt < 4; ++nt)
                    out[(size_t)oc * HW + poff[nt]] = acc[mi][nt][reg];
            }
        }
    }
}

extern "C" void kernel_launch(void* const* d_in, const int* in_sizes, int n_in,
                              void* d_out, int out_size, void* d_ws, size_t ws_size,
                              hipStream_t stream) {
    const float* x           = (const float*)d_in[0];
    const float* temperature = (const float*)d_in[1];
    const float* w_qkv       = (const float*)d_in[2];
    const float* w_dw        = (const float*)d_in[3];
    const float* w_proj      = (const float*)d_in[4];
    float* out = (float*)d_out;

    // per-batch buffers (reused for b=0,1):
    // xT  @ 0          :  77,070,336 B  (HW*192*2)
    // A   @ 77070336   : 216,760,320 B  (540*HW*2)
    // Bw  @ 293830656  : 247,726,080 B  (540*VPLANE*2)
    // Cwt @ 541556736  :  77,070,336 B  (4096*49*192*2)
    if (ws_size < 618627072ull) return;
    unsigned short* xT  = (unsigned short*)d_ws;
    unsigned short* A   = (unsigned short*)((char*)d_ws + 77070336ull);
    unsigned short* Bw  = (unsigned short*)((char*)d_ws + 293830656ull);
    unsigned short* Cwt = (unsigned short*)((char*)d_ws + 541556736ull);

    for (int b = 0; b < 2; ++b) {
        const float* xb = x + (size_t)b * 180 * HW;
        float* ob = out + (size_t)b * 180 * HW;
        transpose_cast_kernel<<<dim3(HW / 64), 256, 0, stream>>>(xb, xT);
        gemm_qkv_kernel<<<dim3(HW / 256, 9), 256, 0, stream>>>(xT, w_qkv, A);
        dw_kernel<<<dim3(64, 540), 256, 0, stream>>>(A, w_dw, Bw);
        attn2_kernel<<<dim3(1024, 6), 256, 0, stream>>>(Bw, temperature, Cwt);
        gemm_proj_kernel<<<dim3(HW / 256, 3), 256, 0, stream>>>(Cwt, w_proj, ob);
    }
}

// Round 6
// 1348.691 us; speedup vs baseline: 3.0696x; 1.1003x over previous
//
#include <hip/hip_runtime.h>

#define HW 200704          // 448*448
#define WIMG 448
#define VPLANE 229376      // 4096 windows * 56 padded pixels (u16 elements)

typedef __attribute__((ext_vector_type(4))) unsigned int u32x4;
typedef __attribute__((ext_vector_type(4))) float f32x4;
typedef __attribute__((ext_vector_type(8))) short s16x8;

static __device__ __forceinline__ unsigned short f2bf(float f) {
    union { float f; unsigned int u; } v; v.f = f;
    unsigned int u = v.u;
    unsigned int r = u + 0x7FFFu + ((u >> 16) & 1u);   // RNE
    return (unsigned short)(r >> 16);
}
static __device__ __forceinline__ float bf2f(unsigned short s) {
    union { unsigned int u; float f; } v; v.u = ((unsigned int)s) << 16;
    return v.f;
}

// ---------------------------------------------------------------------------
// K0: transpose+cast  x fp32 [180][HW] -> xT bf16 [HW][192] (one batch)
// ---------------------------------------------------------------------------
__global__ __launch_bounds__(256) void transpose_cast_kernel(
    const float* __restrict__ x, unsigned short* __restrict__ xT)
{
    const int p0 = blockIdx.x * 64;
    const int tid = threadIdx.x;
    const int pl = tid & 63;

    __shared__ float T[180 * 65];

    for (int ic = tid >> 6; ic < 180; ic += 4)
        T[ic * 65 + pl] = x[(size_t)ic * HW + p0 + pl];
    __syncthreads();

    const int cg = tid >> 6;
    unsigned short* drow = xT + ((size_t)p0 + pl) * 192;
#pragma unroll
    for (int i = 0; i < 6; ++i) {
        int k0 = (cg * 6 + i) * 8;
        unsigned short u[8];
#pragma unroll
        for (int e = 0; e < 8; ++e)
            u[e] = (k0 + e < 180) ? f2bf(T[(k0 + e) * 65 + pl]) : (unsigned short)0;
        *(u32x4*)(drow + k0) = *(const u32x4*)u;
    }
}

// ---------------------------------------------------------------------------
// K1: qkv GEMM via MFMA (one batch). Out: bf16 NCHW [540][HW].
// 1D grid 7056 = 784 px-tiles x 9 oc-tiles, XCD-swizzled so the 9 oc-tiles
// of one px-tile run consecutively on the SAME XCD (xT tile stays in its L2).
// ---------------------------------------------------------------------------
__global__ __launch_bounds__(256) void gemm_qkv_kernel(
    const unsigned short* __restrict__ xT, const float* __restrict__ wq,
    unsigned short* __restrict__ A)
{
    const int d    = blockIdx.x;                 // 0..7055
    const int orig = (d & 7) * 882 + (d >> 3);   // XCD-contiguous chunks
    const int pt   = orig / 9;
    const int ocb  = (orig - pt * 9) * 64;
    const int pix0 = pt * 256;
    const int tid  = threadIdx.x;
    const int l    = tid & 63;
    const int w    = tid >> 6;
    const int r15  = l & 15;
    const int g4   = l >> 4;

    __shared__ __align__(16) unsigned short wlds[64 * 200];
    __shared__ __align__(16) unsigned short xs[256 * 40];

    for (int idx = tid; idx < 64 * 24; idx += 256) {
        int row = idx / 24, ch = idx - (idx / 24) * 24;
        int oc = ocb + row;
        unsigned short u[8];
#pragma unroll
        for (int e = 0; e < 8; ++e) {
            int k = ch * 8 + e;
            u[e] = (oc < 540 && k < 180) ? f2bf(wq[oc * 180 + k]) : (unsigned short)0;
        }
        *(u32x4*)(wlds + row * 200 + ch * 8) = *(const u32x4*)u;
    }

    const unsigned short* srow[4];
#pragma unroll
    for (int i = 0; i < 4; ++i)
        srow[i] = xT + ((size_t)pix0 + i * 64 + (tid >> 2)) * 192 + (tid & 3) * 8;
    const int sdst = (tid >> 2) * 40 + (tid & 3) * 8;

    f32x4 acc[4][4];
#pragma unroll
    for (int mi = 0; mi < 4; ++mi)
#pragma unroll
        for (int nt = 0; nt < 4; ++nt) acc[mi][nt] = (f32x4){0.f, 0.f, 0.f, 0.f};

    for (int ks = 0; ks < 6; ++ks) {
        __syncthreads();
#pragma unroll
        for (int i = 0; i < 4; ++i)
            *(u32x4*)(xs + sdst + i * 64 * 40) = *(const u32x4*)(srow[i] + ks * 32);
        __syncthreads();

        s16x8 aW[4], bX[4];
#pragma unroll
        for (int mi = 0; mi < 4; ++mi)
            aW[mi] = __builtin_bit_cast(s16x8,
                     *(const u32x4*)(wlds + (mi * 16 + r15) * 200 + ks * 32 + g4 * 8));
#pragma unroll
        for (int nt = 0; nt < 4; ++nt)
            bX[nt] = __builtin_bit_cast(s16x8,
                     *(const u32x4*)(xs + (w * 64 + nt * 16 + r15) * 40 + g4 * 8));
#pragma unroll
        for (int mi = 0; mi < 4; ++mi)
#pragma unroll
            for (int nt = 0; nt < 4; ++nt)
                acc[mi][nt] = __builtin_amdgcn_mfma_f32_16x16x32_bf16(
                    aW[mi], bX[nt], acc[mi][nt], 0, 0, 0);
    }

#pragma unroll
    for (int mi = 0; mi < 4; ++mi) {
#pragma unroll
        for (int reg = 0; reg < 4; ++reg) {
            int oc = ocb + mi * 16 + g4 * 4 + reg;
            if (oc < 540) {
                unsigned short* orow = A + (size_t)oc * HW + pix0 + w * 64;
#pragma unroll
                for (int nt = 0; nt < 4; ++nt)
                    orow[nt * 16 + r15] = f2bf(acc[mi][nt][reg]);
            }
        }
    }
}

// ---------------------------------------------------------------------------
// K2: depthwise 3x3 (SAME) + window rearrange (one batch).
// In : bf16 A [540][448][448]
// Out: bf16 Bw [head][part][dc][win][56]  (p 49..55 zero)
// ---------------------------------------------------------------------------
__global__ __launch_bounds__(256) void dw_kernel(
    const unsigned short* __restrict__ A, const float* __restrict__ wdw,
    unsigned short* __restrict__ Bw)
{
    const int wrow = blockIdx.x;   // 0..63
    const int c    = blockIdx.y;   // 0..539
    const int tid  = threadIdx.x;

    const int part = c / 180;
    const int rem  = c - part * 180;
    const int head = rem / 30;
    const int dc   = rem - head * 30;

    __shared__ float Ls[9 * 452];

    float w9[9];
#pragma unroll
    for (int i = 0; i < 9; ++i) w9[i] = wdw[c * 9 + i];

    const int y0 = wrow * 7;
    const unsigned int* Ac32 = (const unsigned int*)(A + (size_t)c * HW);
    for (int idx = tid; idx < 2016; idx += 256) {
        int r  = idx / 224;
        int c2 = idx - r * 224;
        int y  = y0 + r - 1;
        unsigned int v = ((unsigned)y < 448u) ? Ac32[y * 224 + c2] : 0u;
        Ls[r * 452 + 1 + 2 * c2] = bf2f((unsigned short)(v & 0xffffu));
        Ls[r * 452 + 2 + 2 * c2] = bf2f((unsigned short)(v >> 16));
    }
    if (tid < 18) {
        int r = tid >> 1;
        Ls[r * 452 + ((tid & 1) ? 449 : 0)] = 0.f;
    }
    __syncthreads();

    unsigned int* dst = (unsigned int*)(Bw +
        ((size_t)(head * 3 + part) * 30 + dc) * VPLANE + (size_t)wrow * 64 * 56);
#pragma unroll
    for (int k = 0; k < 7; ++k) {
        int o2 = k * 256 + tid;            // u32 index 0..1791
        int wo = o2 / 28;
        int r2 = o2 - wo * 28;
        unsigned short r2v[2];
#pragma unroll
        for (int e = 0; e < 2; ++e) {
            int rm = r2 * 2 + e;
            float acc = 0.f;
            if (rm < 49) {
                int ph = rm / 7, pw = rm - ph * 7;
                int xb = wo * 7 + pw;
                const float* L = Ls + ph * 452 + xb;
                acc = w9[0]*L[0] + w9[1]*L[1] + w9[2]*L[2];
                L += 452;
                acc += w9[3]*L[0] + w9[4]*L[1] + w9[5]*L[2];
                L += 452;
                acc += w9[6]*L[0] + w9[7]*L[1] + w9[8]*L[2];
            }
            r2v[e] = (rm < 49) ? f2bf(acc) : (unsigned short)0;
        }
        dst[o2] = (unsigned int)r2v[0] | ((unsigned int)r2v[1] << 16);
    }
}

// ---------------------------------------------------------------------------
// K3: channel attention (one batch). Block = 4 consecutive windows of one head,
// one wave each. Vectorized b128 staging for Q/K; per-element transpose for V.
// Out: Cwt [win][49][192] bf16 (ch 180..191 zeroed by head==5)
// ---------------------------------------------------------------------------
__global__ __launch_bounds__(256) void attn2_kernel(
    const unsigned short* __restrict__ Bw,
    const float* __restrict__ temperature,
    unsigned short* __restrict__ Cwt)
{
    __shared__ __align__(16) unsigned short lds[4][6144];
    __shared__ float invs[4][64];

    const int w    = threadIdx.x >> 6;
    const int l    = threadIdx.x & 63;
    const int wg   = blockIdx.x;
    const int head = blockIdx.y;
    const int win  = wg * 4 + w;
    const float temp = temperature[head];
    unsigned short* U = lds[w];
    float* inv = invs[w];
    const int r15 = l & 15;
    const int g4  = l >> 4;

    // ---- stage Q/K: 8 b128 per lane (rows>=30 and chunk 7 -> zeros) ----
    {
        const unsigned short* plane0 =
            Bw + (size_t)(head * 3) * 30 * VPLANE + (size_t)win * 56;
#pragma unroll
        for (int i = 0; i < 8; ++i) {
            int part = i >> 2;
            int row  = ((i & 3) << 3) | (l >> 3);   // 0..31
            int c    = l & 7;
            u32x4 v = {0u, 0u, 0u, 0u};
            if (row < 30 && c < 7)
                v = *(const u32x4*)(plane0 + (size_t)(part * 30 + row) * VPLANE + c * 8);
            *(u32x4*)(U + part * 2048 + row * 64 + ((c ^ (row & 7)) << 3)) = v;
        }
    }
    // ---- stage V transposed into Vt [p][32] (swizzled), zero cols 30/31 ----
    {
        const unsigned short* vplane =
            Bw + (size_t)(head * 3 + 2) * 30 * VPLANE + (size_t)win * 56;
        for (int j = 0; j < 23; ++j) {
            int idx = j * 64 + l;
            if (idx < 1470) {
                int dc = idx / 49;
                int p  = idx - dc * 49;
                unsigned short val = vplane[(size_t)dc * VPLANE + p];
                int col = (((dc >> 3) ^ (p & 3)) << 3) | (dc & 7);
                U[4096 + p * 32 + col] = val;
            }
        }
        int c30 = ((3 ^ (l & 3)) << 3) | 6;         // dc=30 slot for p=l
        U[4096 + l * 32 + c30]     = 0;
        U[4096 + l * 32 + c30 + 1] = 0;             // dc=31
    }
    __syncthreads();

    s16x8 aQ[2][2], bK[2][2];
#pragma unroll
    for (int mi = 0; mi < 2; ++mi)
#pragma unroll
        for (int kk = 0; kk < 2; ++kk) {
            int r  = mi * 16 + r15;
            int gk = kk * 4 + g4;
            int so = ((gk ^ (r & 7)) << 3);
            aQ[mi][kk] = __builtin_bit_cast(s16x8, *(const u32x4*)(U + r * 64 + so));
            bK[mi][kk] = __builtin_bit_cast(s16x8, *(const u32x4*)(U + 2048 + r * 64 + so));
        }

    f32x4 s[2][2], dq[2], dk[2];
#pragma unroll
    for (int mi = 0; mi < 2; ++mi) {
        dq[mi] = (f32x4){0.f, 0.f, 0.f, 0.f};
        dk[mi] = (f32x4){0.f, 0.f, 0.f, 0.f};
#pragma unroll
        for (int nj = 0; nj < 2; ++nj) s[mi][nj] = (f32x4){0.f, 0.f, 0.f, 0.f};
    }

#pragma unroll
    for (int kk = 0; kk < 2; ++kk) {
#pragma unroll
        for (int mi = 0; mi < 2; ++mi) {
#pragma unroll
            for (int nj = 0; nj < 2; ++nj)
                s[mi][nj] = __builtin_amdgcn_mfma_f32_16x16x32_bf16(
                    aQ[mi][kk], bK[nj][kk], s[mi][nj], 0, 0, 0);
            dq[mi] = __builtin_amdgcn_mfma_f32_16x16x32_bf16(
                aQ[mi][kk], aQ[mi][kk], dq[mi], 0, 0, 0);
            dk[mi] = __builtin_amdgcn_mfma_f32_16x16x32_bf16(
                bK[mi][kk], bK[mi][kk], dk[mi], 0, 0, 0);
        }
    }

#pragma unroll
    for (int mi = 0; mi < 2; ++mi)
#pragma unroll
        for (int reg = 0; reg < 4; ++reg) {
            int row = g4 * 4 + reg;
            if (row == r15) {
                inv[mi * 16 + row]      = 1.f / fmaxf(sqrtf(dq[mi][reg]), 1e-12f);
                inv[32 + mi * 16 + row] = 1.f / fmaxf(sqrtf(dk[mi][reg]), 1e-12f);
            }
        }
    __syncthreads();

    float pr[2][2][4];
    float cinvk0 = inv[32 + r15];
    float cinvk1 = inv[32 + 16 + r15];
#pragma unroll
    for (int mi = 0; mi < 2; ++mi)
#pragma unroll
        for (int reg = 0; reg < 4; ++reg) {
            float qi = inv[mi * 16 + g4 * 4 + reg];
            float v0 = s[mi][0][reg] * qi * cinvk0 * temp;
            float v1 = s[mi][1][reg] * qi * cinvk1 * temp;
            if (16 + r15 >= 30) v1 = -1e30f;
            float m = fmaxf(v0, v1);
#pragma unroll
            for (int off = 1; off < 16; off <<= 1) m = fmaxf(m, __shfl_xor(m, off));
            float e0 = __expf(v0 - m);
            float e1 = __expf(v1 - m);
            float sum = e0 + e1;
#pragma unroll
            for (int off = 1; off < 16; off <<= 1) sum += __shfl_xor(sum, off);
            float rs = 1.f / sum;
            pr[mi][0][reg] = e0 * rs;
            pr[mi][1][reg] = e1 * rs;
        }

#pragma unroll
    for (int mi = 0; mi < 2; ++mi)
#pragma unroll
        for (int nj = 0; nj < 2; ++nj)
#pragma unroll
            for (int reg = 0; reg < 4; ++reg) {
                int row = mi * 16 + g4 * 4 + reg;
                int col = nj * 16 + r15;
                int scol = (((col >> 3) ^ (row & 3)) << 3) | (col & 7);
                U[row * 32 + scol] = f2bf(pr[mi][nj][reg]);
            }
    __syncthreads();

    s16x8 aP[2], bV[4];
#pragma unroll
    for (int mi = 0; mi < 2; ++mi) {
        int i = mi * 16 + r15;
        aP[mi] = __builtin_bit_cast(s16x8,
                 *(const u32x4*)(U + i * 32 + ((g4 ^ (i & 3)) << 3)));
    }
#pragma unroll
    for (int nt = 0; nt < 4; ++nt) {
        int p = nt * 16 + r15;
        bV[nt] = __builtin_bit_cast(s16x8,
                 *(const u32x4*)(U + 4096 + p * 32 + ((g4 ^ (p & 3)) << 3)));
    }
    f32x4 o[2][4];
#pragma unroll
    for (int mi = 0; mi < 2; ++mi)
#pragma unroll
        for (int nt = 0; nt < 4; ++nt) {
            o[mi][nt] = (f32x4){0.f, 0.f, 0.f, 0.f};
            o[mi][nt] = __builtin_amdgcn_mfma_f32_16x16x32_bf16(
                aP[mi], bV[nt], o[mi][nt], 0, 0, 0);
        }

    unsigned short* dst = Cwt + ((size_t)win * 49) * 192 + head * 30;
#pragma unroll
    for (int mi = 0; mi < 2; ++mi) {
        int ch0 = mi * 16 + g4 * 4;
#pragma unroll
        for (int nt = 0; nt < 4; ++nt) {
            int p = nt * 16 + r15;
            if (p < 49) {
                unsigned int lo = (unsigned int)f2bf(o[mi][nt][0]) |
                                  ((unsigned int)f2bf(o[mi][nt][1]) << 16);
                *(unsigned int*)(dst + (size_t)p * 192 + ch0) = lo;
                if (ch0 + 2 < 30) {
                    unsigned int hi = (unsigned int)f2bf(o[mi][nt][2]) |
                                      ((unsigned int)f2bf(o[mi][nt][3]) << 16);
                    *(unsigned int*)(dst + (size_t)p * 192 + ch0 + 2) = hi;
                }
            }
        }
    }
    if (head == 5 && g4 == 0) {
        unsigned short* zrow = Cwt + ((size_t)win * 49) * 192 + 180;
#pragma unroll
        for (int nt = 0; nt < 4; ++nt) {
            int p = nt * 16 + r15;
            if (p < 49) {
                *(unsigned int*)(zrow + (size_t)p * 192 + 0) = 0u;
                *(unsigned int*)(zrow + (size_t)p * 192 + 2) = 0u;
                *(unsigned int*)(zrow + (size_t)p * 192 + 4) = 0u;
            }
        }
    }
}

// ---------------------------------------------------------------------------
// K4: proj GEMM via MFMA (one batch). B-op rows from Cwt [win][49][192].
// 1D grid 2352 = 784 px-tiles x 3 oc-tiles, XCD-swizzled (same scheme as K1).
// Out: fp32 NCHW with window->image scatter.
// ---------------------------------------------------------------------------
__global__ __launch_bounds__(256) void gemm_proj_kernel(
    const unsigned short* __restrict__ Cwt, const float* __restrict__ wp,
    float* __restrict__ out)
{
    const int d    = blockIdx.x;                 // 0..2351
    const int orig = (d & 7) * 294 + (d >> 3);
    const int pt   = orig / 3;
    const int ocb  = (orig - pt * 3) * 64;
    const int pix0 = pt * 256;
    const int tid  = threadIdx.x;
    const int l    = tid & 63;
    const int w    = tid >> 6;
    const int r15  = l & 15;
    const int g4   = l >> 4;

    __shared__ __align__(16) unsigned short wlds[64 * 200];
    __shared__ __align__(16) unsigned short xs[256 * 40];

    for (int idx = tid; idx < 64 * 24; idx += 256) {
        int row = idx / 24, ch = idx - (idx / 24) * 24;
        int oc = ocb + row;
        unsigned short u[8];
#pragma unroll
        for (int e = 0; e < 8; ++e) {
            int k = ch * 8 + e;
            u[e] = (oc < 180 && k < 180) ? f2bf(wp[oc * 180 + k]) : (unsigned short)0;
        }
        *(u32x4*)(wlds + row * 200 + ch * 8) = *(const u32x4*)u;
    }

    const unsigned short* srow[4];
#pragma unroll
    for (int i = 0; i < 4; ++i) {
        int P = pix0 + i * 64 + (tid >> 2);
        int win = P / 49, p = P - win * 49;
        srow[i] = Cwt + ((size_t)win * 49 + p) * 192 + (tid & 3) * 8;
    }
    const int sdst = (tid >> 2) * 40 + (tid & 3) * 8;

    f32x4 acc[4][4];
#pragma unroll
    for (int mi = 0; mi < 4; ++mi)
#pragma unroll
        for (int nt = 0; nt < 4; ++nt) acc[mi][nt] = (f32x4){0.f, 0.f, 0.f, 0.f};

    for (int ks = 0; ks < 6; ++ks) {
        __syncthreads();
#pragma unroll
        for (int i = 0; i < 4; ++i)
            *(u32x4*)(xs + sdst + i * 64 * 40) = *(const u32x4*)(srow[i] + ks * 32);
        __syncthreads();

        s16x8 aW[4], bX[4];
#pragma unroll
        for (int mi = 0; mi < 4; ++mi)
            aW[mi] = __builtin_bit_cast(s16x8,
                     *(const u32x4*)(wlds + (mi * 16 + r15) * 200 + ks * 32 + g4 * 8));
#pragma unroll
        for (int nt = 0; nt < 4; ++nt)
            bX[nt] = __builtin_bit_cast(s16x8,
                     *(const u32x4*)(xs + (w * 64 + nt * 16 + r15) * 40 + g4 * 8));
#pragma unroll
        for (int mi = 0; mi < 4; ++mi)
#pragma unroll
            for (int nt = 0; nt < 4; ++nt)
                acc[mi][nt] = __builtin_amdgcn_mfma_f32_16x16x32_bf16(
                    aW[mi], bX[nt], acc[mi][nt], 0, 0, 0);
    }

    int poff[4];
#pragma unroll
    for (int nt = 0; nt < 4; ++nt) {
        int P = pix0 + w * 64 + nt * 16 + r15;
        int win = P / 49, p = P - win * 49;
        int ph = p / 7, pw2 = p - ph * 7;
        poff[nt] = ((win >> 6) * 7 + ph) * WIMG + (win & 63) * 7 + pw2;
    }
#pragma unroll
    for (int mi = 0; mi < 4; ++mi) {
#pragma unroll
        for (int reg = 0; reg < 4; ++reg) {
            int oc = ocb + mi * 16 + g4 * 4 + reg;
            if (oc < 180) {
#pragma unroll
                for (int nt = 0; nt < 4; ++nt)
                    out[(size_t)oc * HW + poff[nt]] = acc[mi][nt][reg];
            }
        }
    }
}

extern "C" void kernel_launch(void* const* d_in, const int* in_sizes, int n_in,
                              void* d_out, int out_size, void* d_ws, size_t ws_size,
                              hipStream_t stream) {
    const float* x           = (const float*)d_in[0];
    const float* temperature = (const float*)d_in[1];
    const float* w_qkv       = (const float*)d_in[2];
    const float* w_dw        = (const float*)d_in[3];
    const float* w_proj      = (const float*)d_in[4];
    float* out = (float*)d_out;

    // per-batch buffers (reused for b=0,1):
    // xT  @ 0          :  77,070,336 B
    // A   @ 77070336   : 216,760,320 B
    // Bw  @ 293830656  : 247,726,080 B
    // Cwt @ 541556736  :  77,070,336 B
    if (ws_size < 618627072ull) return;
    unsigned short* xT  = (unsigned short*)d_ws;
    unsigned short* A   = (unsigned short*)((char*)d_ws + 77070336ull);
    unsigned short* Bw  = (unsigned short*)((char*)d_ws + 293830656ull);
    unsigned short* Cwt = (unsigned short*)((char*)d_ws + 541556736ull);

    for (int b = 0; b < 2; ++b) {
        const float* xb = x + (size_t)b * 180 * HW;
        float* ob = out + (size_t)b * 180 * HW;
        transpose_cast_kernel<<<dim3(HW / 64), 256, 0, stream>>>(xb, xT);
        gemm_qkv_kernel<<<dim3(7056), 256, 0, stream>>>(xT, w_qkv, A);
        dw_kernel<<<dim3(64, 540), 256, 0, stream>>>(A, w_dw, Bw);
        attn2_kernel<<<dim3(1024, 6), 256, 0, stream>>>(Bw, temperature, Cwt);
        gemm_proj_kernel<<<dim3(2352), 256, 0, stream>>>(Cwt, w_proj, ob);
    }
}